// Round 17
// baseline (1234.695 us; speedup 1.0000x reference)
//
#include <hip/hip_runtime.h>
#include <hip/hip_bf16.h>
#include <hip/hip_fp16.h>

// Problem constants
#define N_TOK 32768      // B*T
#define D_DIM 768
#define H_DIM 3072
#define E_NUM 4
#define MT_PAD (N_TOK + 512)   // max padded rows per pass (4 segments, 128-aligned)

// Tiled operand layout: one K-tile block = [g(4)][128 rows][8 k] f16 = 4096 elems
// = 8 KB CONTIGUOUS (matches MFMA LDS fragment layout; staging is lane-contiguous).
#define TILE_E 4096

typedef _Float16 f16_t;
typedef _Float16 f16x8 __attribute__((ext_vector_type(8)));
typedef float f32x4 __attribute__((ext_vector_type(4)));

__device__ __forceinline__ f16_t f2h(float f) { return (f16_t)f; }

// async global->LDS, 16B per lane; GLOBAL src per-lane, LDS dest wave-uniform base (+lane*16)
__device__ __forceinline__ void gload16(const void* g, void* l) {
  __builtin_amdgcn_global_load_lds(
      (const __attribute__((address_space(1))) void*)g,
      (__attribute__((address_space(3))) void*)l,
      16, 0, 0);
}

// Raw barrier pinned against compiler reordering (m201 discipline, rule #18).
__device__ __forceinline__ void pipe_barrier() {
  asm volatile("" ::: "memory");
  __builtin_amdgcn_sched_barrier(0);
  __builtin_amdgcn_s_barrier();
  __builtin_amdgcn_sched_barrier(0);
  asm volatile("" ::: "memory");
}

// Bijective XCD-aware remap (m204): consecutive tile ids (ntile-fastest) land on one XCD.
__device__ __forceinline__ int xcd_swizzle(int f, int nwg) {
  const int q = nwg >> 3, r = nwg & 7;
  const int xcd = f & 7, pos = f >> 3;
  return (xcd < r ? xcd * (q + 1) : r * (q + 1) + (xcd - r) * q) + pos;
}

// meta layout (ints): 8..12 pb0 | 13..17 pb1 | 18..21 cur0 | 22..25 cur1

// ---------------- init: sentinel-fill index lists ----------------
__global__ __launch_bounds__(256) void fill_kernel(unsigned* __restrict__ idx0,
                                                   unsigned* __restrict__ idx1) {
  const int t = blockIdx.x * 256 + threadIdx.x;
  for (int i = t; i < MT_PAD; i += gridDim.x * 256) {
    idx0[i] = 0xFFFFFFFFu;
    idx1[i] = 0xFFFFFFFFu;
  }
}

// ---------------- transform: fp32 [E][K][N] -> tiled f16 [E][nt][kt][g][128][8] ----
__global__ __launch_bounds__(256) void transform_kernel(
    const float* __restrict__ in, f16_t* __restrict__ outT,
    int R, int C, int NT, int KT) {   // R = K rows, C = N cols of input
  __shared__ float tile[32][33];
  const int ez = blockIdx.z;
  in += (size_t)ez * R * C;
  const int c0 = blockIdx.x * 32, r0 = blockIdx.y * 32;
  const int tc = threadIdx.x & 31, tr = threadIdx.x >> 5;
#pragma unroll
  for (int i = 0; i < 32; i += 8)
    tile[tr + i][tc] = in[(size_t)(r0 + tr + i) * C + c0 + tc];
  __syncthreads();
  const int kt = r0 >> 5, g = tc >> 3, kk = tc & 7;   // k = r0 + tc
#pragma unroll
  for (int i = 0; i < 32; i += 8) {
    const int n = c0 + tr + i;
    const int nt = n >> 7, rl = n & 127;
    outT[(((size_t)(ez * NT + nt)) * KT + kt) * TILE_E + g * 1024 + rl * 8 + kk]
        = f2h(tile[tc][tr + i]);
  }
}

// ---------------- router: softmax, top-2, pair info, block-partial counts (NO atomics) ----
__global__ __launch_bounds__(256) void router_kernel(
    const float* __restrict__ x, const float* __restrict__ rw, const float* __restrict__ rb,
    float* __restrict__ wcomb, int* __restrict__ pairinfo,
    float* __restrict__ psum_part, int* __restrict__ cnt_part,
    int* __restrict__ cnt0_part, int* __restrict__ cnt1_part) {
  __shared__ float rwT[E_NUM][D_DIM];
  __shared__ float prW[4][E_NUM];
  __shared__ int   cnW[4][E_NUM];
  __shared__ int   cn0W[4][E_NUM];
  __shared__ int   cn1W[4][E_NUM];
  const int tid = threadIdx.x;
  for (int i = tid; i < D_DIM * E_NUM; i += 256) {
    int k = i >> 2, e = i & 3;
    rwT[e][k] = rw[i];
  }
  __syncthreads();
  const int lane = tid & 63, wv_ = tid >> 6;
  float pacc[E_NUM] = {0.f, 0.f, 0.f, 0.f};
  int   cacc[E_NUM] = {0, 0, 0, 0};
  int   c0acc[E_NUM] = {0, 0, 0, 0};
  int   c1acc[E_NUM] = {0, 0, 0, 0};
  const int tok0 = blockIdx.x * 32 + wv_ * 8;
  for (int t = 0; t < 8; ++t) {
    const int m = tok0 + t;
    const float* xr = x + (size_t)m * D_DIM;
    float s0 = 0.f, s1 = 0.f, s2 = 0.f, s3 = 0.f;
#pragma unroll
    for (int i = 0; i < D_DIM / 64; ++i) {
      int k = lane + i * 64;
      float xv = xr[k];
      s0 += xv * rwT[0][k]; s1 += xv * rwT[1][k];
      s2 += xv * rwT[2][k]; s3 += xv * rwT[3][k];
    }
#pragma unroll
    for (int off = 32; off >= 1; off >>= 1) {
      s0 += __shfl_xor(s0, off); s1 += __shfl_xor(s1, off);
      s2 += __shfl_xor(s2, off); s3 += __shfl_xor(s3, off);
    }
    if (lane == 0) {
      float lg[4] = {s0 + rb[0], s1 + rb[1], s2 + rb[2], s3 + rb[3]};
      float mx = fmaxf(fmaxf(lg[0], lg[1]), fmaxf(lg[2], lg[3]));
      float p[4]; float den = 0.f;
#pragma unroll
      for (int e = 0; e < 4; ++e) { p[e] = expf(lg[e] - mx); den += p[e]; }
      float inv = 1.f / den;
#pragma unroll
      for (int e = 0; e < 4; ++e) p[e] *= inv;
      int i1 = 0;
#pragma unroll
      for (int e = 1; e < 4; ++e) if (p[e] > p[i1]) i1 = e;
      int i2 = (i1 == 0) ? 1 : 0;
#pragma unroll
      for (int e = 0; e < 4; ++e) if (e != i1 && p[e] > p[i2]) i2 = e;
      float4 wvout;
      wvout.x = (0 == i1 || 0 == i2) ? p[0] : 0.f;
      wvout.y = (1 == i1 || 1 == i2) ? p[1] : 0.f;
      wvout.z = (2 == i1 || 2 == i2) ? p[2] : 0.f;
      wvout.w = (3 == i1 || 3 == i2) ? p[3] : 0.f;
      ((float4*)wcomb)[m] = wvout;
      const int emin = (i1 < i2) ? i1 : i2;
      const int emax = (i1 < i2) ? i2 : i1;
      pairinfo[m] = emin | (emax << 4);
      c0acc[emin]++; c1acc[emax]++;
#pragma unroll
      for (int e = 0; e < 4; ++e) pacc[e] += p[e];
      cacc[i1]++; cacc[i2]++;
    }
  }
  if (lane == 0) {
#pragma unroll
    for (int e = 0; e < 4; ++e) {
      prW[wv_][e] = pacc[e]; cnW[wv_][e] = cacc[e];
      cn0W[wv_][e] = c0acc[e]; cn1W[wv_][e] = c1acc[e];
    }
  }
  __syncthreads();
  if (tid < 4) {
    float ps = prW[0][tid] + prW[1][tid] + prW[2][tid] + prW[3][tid];
    int   cs = cnW[0][tid] + cnW[1][tid] + cnW[2][tid] + cnW[3][tid];
    psum_part[blockIdx.x * 4 + tid] = ps;
    cnt_part[blockIdx.x * 4 + tid]  = cs;
    cnt0_part[blockIdx.x * 4 + tid] = cn0W[0][tid] + cn0W[1][tid] + cn0W[2][tid] + cn0W[3][tid];
    cnt1_part[blockIdx.x * 4 + tid] = cn1W[0][tid] + cn1W[1][tid] + cn1W[2][tid] + cn1W[3][tid];
  }
}

// ---------------- loss reduction (1 wave, deterministic order) ----------------
__global__ void loss_kernel(const float* __restrict__ psum_part,
                            const int* __restrict__ cnt_part,
                            float* __restrict__ loss_out, int nblk) {
  const int lane = threadIdx.x;
  float ps[4] = {0.f, 0.f, 0.f, 0.f};
  int   cs[4] = {0, 0, 0, 0};
  for (int r = lane; r < nblk; r += 64) {
#pragma unroll
    for (int e = 0; e < 4; ++e) { ps[e] += psum_part[r * 4 + e]; cs[e] += cnt_part[r * 4 + e]; }
  }
#pragma unroll
  for (int off = 32; off >= 1; off >>= 1) {
#pragma unroll
    for (int e = 0; e < 4; ++e) {
      ps[e] += __shfl_xor(ps[e], off);
      cs[e] += __shfl_xor(cs[e], off);
    }
  }
  if (lane == 0) {
    float loss = 0.f;
#pragma unroll
    for (int e = 0; e < 4; ++e) {
      float mean = ps[e] / (float)N_TOK;
      float frac = (float)cs[e] / (float)(N_TOK * 2);
      loss += mean * frac;
    }
    loss_out[0] = 4.f * loss;
  }
}

// ---------------- setup: reduce block-partial counts -> 128-padded bases + cursors ----
__global__ __launch_bounds__(256) void setup_kernel(const int* __restrict__ cnt0_part,
                                                    const int* __restrict__ cnt1_part,
                                                    int* __restrict__ meta, int nblk) {
  __shared__ int sh[8][32];
  const int ch = threadIdx.x >> 5, ln = threadIdx.x & 31;
  const int* src = (ch < 4) ? cnt0_part : cnt1_part;
  const int e = ch & 3;
  int s = 0;
  for (int b = ln; b < nblk; b += 32) s += src[b * 4 + e];
  sh[ch][ln] = s;
  __syncthreads();
  if (threadIdx.x == 0) {
    int c[8];
    for (int c2 = 0; c2 < 8; ++c2) {
      int t = 0;
      for (int l = 0; l < 32; ++l) t += sh[c2][l];
      c[c2] = t;
    }
    int pb = 0; meta[8] = 0;
    for (int e2 = 0; e2 < 4; ++e2) { pb += (c[e2] + 127) & ~127; meta[9 + e2] = pb; }
    pb = 0; meta[13] = 0;
    for (int e2 = 0; e2 < 4; ++e2) { pb += (c[4 + e2] + 127) & ~127; meta[14 + e2] = pb; }
    for (int e2 = 0; e2 < 4; ++e2) { meta[18 + e2] = meta[8 + e2]; meta[22 + e2] = meta[13 + e2]; }
  }
}

// ---------------- scatter: ballot ranks + ONE atomic per (block,channel) ----------
__global__ __launch_bounds__(256) void scatter_kernel(const int* __restrict__ pairinfo,
                                                      int* __restrict__ meta,
                                                      unsigned* __restrict__ idx0,
                                                      unsigned* __restrict__ idx1) {
  __shared__ int wcnt[2][4][4];   // [pass][wave][expert]
  __shared__ int blkbase[2][4];   // [pass][expert]
  const int tid = threadIdx.x, lane = tid & 63, wv = tid >> 6;
  const int t = blockIdx.x * 256 + tid;
  const int info = pairinfo[t];
  const int esel0 = info & 15, esel1 = info >> 4;
  int rank0 = 0, rank1 = 0;
#pragma unroll
  for (int e = 0; e < 4; ++e) {
    unsigned long long m0 = __ballot(esel0 == e);
    if (esel0 == e) rank0 = __popcll(m0 & ((1ull << lane) - 1ull));
    unsigned long long m1 = __ballot(esel1 == e);
    if (esel1 == e) rank1 = __popcll(m1 & ((1ull << lane) - 1ull));
    if (lane == 0) { wcnt[0][wv][e] = __popcll(m0); wcnt[1][wv][e] = __popcll(m1); }
  }
  __syncthreads();
  int wbase0 = 0, wbase1 = 0;
  for (int w = 0; w < wv; ++w) { wbase0 += wcnt[0][w][esel0]; wbase1 += wcnt[1][w][esel1]; }
  if (tid < 8) {
    const int p = tid >> 2, e = tid & 3;
    const int tot = wcnt[p][0][e] + wcnt[p][1][e] + wcnt[p][2][e] + wcnt[p][3][e];
    blkbase[p][e] = atomicAdd(&meta[(p ? 22 : 18) + e], tot);
  }
  __syncthreads();
  idx0[blkbase[0][esel0] + wbase0 + rank0] = (unsigned)t;
  idx1[blkbase[1][esel1] + wbase1 + rank1] = (unsigned)t;
}

// ---------------- gather: x rows (by token) -> xg tiled f16 [mt][kt24][g][128][8] ----
__global__ __launch_bounds__(256) void gather_kernel(
    const float* __restrict__ x, const unsigned* __restrict__ idx_p,
    f16_t* __restrict__ xg, int srow) {
  __shared__ unsigned idx_s[128];
  const int tid = threadIdx.x, mt = blockIdx.x;
  if (tid < 128) {
    const int gr = srow + mt * 128 + tid;
    idx_s[tid] = (gr < MT_PAD) ? idx_p[gr] : 0xFFFFFFFFu;
  }
  __syncthreads();
  f16_t* dst = xg + (size_t)mt * 24 * TILE_E;
  for (int i = tid; i < 128 * 96; i += 256) {
    const int r = i / 96, grp = i - r * 96;   // grp: 8-elem k-group (768/8)
    const unsigned v = idx_s[r];
    const float* src = x + (size_t)((v < N_TOK) ? v : 0u) * D_DIM + grp * 8;
    float4 f0 = ((const float4*)src)[0];
    float4 f1 = ((const float4*)src)[1];
    f16x8 h;
    h[0] = f2h(f0.x); h[1] = f2h(f0.y); h[2] = f2h(f0.z); h[3] = f2h(f0.w);
    h[4] = f2h(f1.x); h[5] = f2h(f1.y); h[6] = f2h(f1.z); h[7] = f2h(f1.w);
    const int kt = grp >> 2, g = grp & 3;
    *(f16x8*)&dst[(size_t)kt * TILE_E + g * 1024 + r * 8] = h;
  }
}

#define BM 128
#define BN 128

#define MFMA_HALF(AvBase, BvBase)                                                   \
  {                                                                                 \
    const f16x8* Av = (const f16x8*)(AvBase);                                       \
    const f16x8* Bv = (const f16x8*)(BvBase);                                       \
    const int gsel = (lane >> 4) * 128;                                             \
    f16x8 a[4], b[4];                                                               \
    _Pragma("unroll")                                                               \
    for (int mf = 0; mf < 4; ++mf) a[mf] = Av[gsel + wr * 64 + mf * 16 + (lane & 15)]; \
    _Pragma("unroll")                                                               \
    for (int nf = 0; nf < 4; ++nf) b[nf] = Bv[gsel + wc * 64 + nf * 16 + (lane & 15)]; \
    _Pragma("unroll")                                                               \
    for (int mf = 0; mf < 4; ++mf)                                                  \
      _Pragma("unroll")                                                             \
      for (int nf = 0; nf < 4; ++nf)                                                \
        acc[mf][nf] = __builtin_amdgcn_mfma_f32_16x16x32_f16(a[mf], b[nf], acc[mf][nf], 0, 0, 0); \
  }

// GEMM1 (sparse, r16 structure = CONTROL): BK=64, single-buffer, plain sync.
__global__ __launch_bounds__(256, 3) void gemm1_kernel(
    const f16_t* __restrict__ xg, const f16_t* __restrict__ W1T,
    const float* __restrict__ b1, const int* __restrict__ pb_p,
    f16_t* __restrict__ HwP, int srow) {
  __shared__ __align__(16) f16_t As[2 * TILE_E];
  __shared__ __align__(16) f16_t Bs[2 * TILE_E];
  const int tid = threadIdx.x, lane = tid & 63, wid = tid >> 6;
  const int wg = xcd_swizzle(blockIdx.x, gridDim.x);
  const int ntile = wg % 24, mtile = wg / 24;
  const int m128 = srow + mtile * BM;
  if (m128 >= pb_p[4]) return;
  int e = 0;
  while (e < 3 && m128 >= pb_p[e + 1]) ++e;
  const int n0 = ntile * BN;   // within H_DIM

  const f16_t* abase = xg + (size_t)mtile * 24 * TILE_E + lane * 8;
  const f16_t* bbase = W1T + (size_t)(e * 24 + ntile) * 24 * TILE_E + lane * 8;

  auto stage = [&](int kt, int h) {
    const f16_t* a = abase + (size_t)kt * TILE_E;
    const f16_t* b = bbase + (size_t)kt * TILE_E;
    gload16(a + wid * 512,        &As[h * TILE_E + wid * 512]);
    gload16(a + 2048 + wid * 512, &As[h * TILE_E + 2048 + wid * 512]);
    gload16(b + wid * 512,        &Bs[h * TILE_E + wid * 512]);
    gload16(b + 2048 + wid * 512, &Bs[h * TILE_E + 2048 + wid * 512]);
  };

  const int wr = wid >> 1, wc = wid & 1;
  f32x4 acc[4][4] = {};

  float b1v[4];
#pragma unroll
  for (int nf = 0; nf < 4; ++nf)
    b1v[nf] = b1[e * H_DIM + n0 + wc * 64 + nf * 16 + (lane & 15)];

  const int NT2 = (D_DIM / 32) / 2;  // 12 iterations of BK=64
  for (int t = 0; t < NT2; ++t) {
    stage(2 * t, 0);
    stage(2 * t + 1, 1);
    __syncthreads();          // vmcnt drain + barrier
    MFMA_HALF(As, Bs);
    MFMA_HALF(As + TILE_E, Bs + TILE_E);
    __syncthreads();          // all waves done reading before next overwrite
  }

  const int colb = wc * 64 + (lane & 15);
#pragma unroll
  for (int mf = 0; mf < 4; ++mf) {
    const int rowb = wr * 64 + mf * 16 + ((lane >> 4) << 2);
#pragma unroll
    for (int nf = 0; nf < 4; ++nf) {
      const int col = n0 + colb + nf * 16;
      const int kt = col >> 5, g = (col >> 3) & 3, kk = col & 7;
#pragma unroll
      for (int j = 0; j < 4; ++j) {
        const int row = rowb + j;
        float v = acc[mf][nf][j] + b1v[nf];
        float gel = 0.5f * v * (1.0f + erff(v * 0.70710678118654752440f));
        HwP[((size_t)(mtile * 96 + kt)) * TILE_E + g * 1024 + row * 8 + kk] = f2h(gel);
      }
    }
  }
}

// GEMM2 (sparse, EXPERIMENT): 3-buffer 32-k rotation, ONE barrier + counted
// vmcnt(4) per 16-MFMA step. Prologue stages steps 0,1; step t: vmcnt(4)
// (step-t loads landed, step-t+1's 4 still in flight - never drains to 0),
// barrier, stage(t+2 -> freed buffer), 16 MFMA. Loads overlap 1.3 steps of
// compute + latency -> stage stall ~eliminated; barriers halved vs r16.
__global__ __launch_bounds__(256, 3) void gemm2_kernel(
    const f16_t* __restrict__ HwP, const f16_t* __restrict__ W2T,
    const float* __restrict__ b2, const float* __restrict__ wcomb,
    const unsigned* __restrict__ idx_p, const int* __restrict__ pb_p,
    float* __restrict__ out, int srow, int doAdd) {
  __shared__ __align__(16) f16_t As[3][TILE_E];
  __shared__ __align__(16) f16_t Bs[3][TILE_E];
  __shared__ unsigned idx_s[BM];
  __shared__ float w_s[BM];
  const int tid = threadIdx.x, lane = tid & 63, wid = tid >> 6;
  const int wg = xcd_swizzle(blockIdx.x, gridDim.x);
  const int ntile = wg % 6, mtile = wg / 6;
  const int m128 = srow + mtile * BM;
  if (m128 >= pb_p[4]) return;
  int e = 0;
  while (e < 3 && m128 >= pb_p[e + 1]) ++e;
  const int n0 = ntile * BN;   // within D_DIM

  if (tid < BM) idx_s[tid] = idx_p[m128 + tid];
  __syncthreads();
  if (tid < BM) {
    unsigned v = idx_s[tid];
    w_s[tid] = (v < N_TOK) ? wcomb[v * 4 + e] : 0.f;
  }

  const f16_t* abase = HwP + (size_t)mtile * 96 * TILE_E + lane * 8;
  const f16_t* bbase = W2T + (size_t)(e * 6 + ntile) * 96 * TILE_E + lane * 8;

  auto stage = [&](int kt, int buf) {
    const f16_t* a = abase + (size_t)kt * TILE_E;
    const f16_t* b = bbase + (size_t)kt * TILE_E;
    gload16(a + wid * 512,        &As[buf][wid * 512]);
    gload16(a + 2048 + wid * 512, &As[buf][2048 + wid * 512]);
    gload16(b + wid * 512,        &Bs[buf][wid * 512]);
    gload16(b + 2048 + wid * 512, &Bs[buf][2048 + wid * 512]);
  };

  const int wr = wid >> 1, wc = wid & 1;
  f32x4 acc[4][4] = {};

  float b2v[4];
#pragma unroll
  for (int nf = 0; nf < 4; ++nf)
    b2v[nf] = b2[e * D_DIM + n0 + wc * 64 + nf * 16 + (lane & 15)];

  stage(0, 0);
  stage(1, 1);
  const int NT = H_DIM / 32;   // 96 steps of 32-k
  int cur = 0;
  for (int t = 0; t < NT; ++t) {
    if (t + 1 < NT) { asm volatile("s_waitcnt vmcnt(4)" ::: "memory"); }
    else            { asm volatile("s_waitcnt vmcnt(0)" ::: "memory"); }
    pipe_barrier();           // all waves' step-t writes landed; buf[(t+2)%3] free
    if (t + 2 < NT) stage(t + 2, (t + 2) % 3);
    MFMA_HALF(As[cur], Bs[cur]);
    cur = (cur == 2) ? 0 : cur + 1;
  }

  const int colb = wc * 64 + (lane & 15);
#pragma unroll
  for (int mf = 0; mf < 4; ++mf) {
    const int rowb = wr * 64 + mf * 16 + ((lane >> 4) << 2);
#pragma unroll
    for (int nf = 0; nf < 4; ++nf) {
      const int col = n0 + colb + nf * 16;
#pragma unroll
      for (int j = 0; j < 4; ++j) {
        const int row = rowb + j;
        const unsigned v = idx_s[row];
        if (v < N_TOK) {
          float contrib = w_s[row] * (acc[mf][nf][j] + b2v[nf]);
          float* po = out + (size_t)v * D_DIM + col;
          if (doAdd) *po += contrib; else *po = contrib;
        }
      }
    }
  }
}

// ---------------- launch ----------------
extern "C" void kernel_launch(void* const* d_in, const int* in_sizes, int n_in,
                              void* d_out, int out_size, void* d_ws, size_t ws_size,
                              hipStream_t stream) {
  const float* x  = (const float*)d_in[0];
  const float* rw = (const float*)d_in[1];
  const float* rb = (const float*)d_in[2];
  const float* W1 = (const float*)d_in[3];
  const float* b1 = (const float*)d_in[4];
  const float* W2 = (const float*)d_in[5];
  const float* b2 = (const float*)d_in[6];
  float* out = (float*)d_out;

  char* ws = (char*)d_ws;
  size_t off = 0;
  auto alloc = [&](size_t bytes) -> void* {
    void* p = ws + off;
    off = (off + bytes + 255) & ~(size_t)255;
    return p;
  };
  f16_t* W1T = (f16_t*)alloc((size_t)E_NUM * D_DIM * H_DIM * sizeof(f16_t));
  f16_t* W2T = (f16_t*)alloc((size_t)E_NUM * D_DIM * H_DIM * sizeof(f16_t));
  float* wcomb = (float*)alloc((size_t)N_TOK * E_NUM * sizeof(float));
  float* psum_part = (float*)alloc((size_t)(N_TOK / 32) * 4 * sizeof(float));
  int*   cnt_part  = (int*)alloc((size_t)(N_TOK / 32) * 4 * sizeof(int));
  int*   cnt0_part = (int*)alloc((size_t)(N_TOK / 32) * 4 * sizeof(int));
  int*   cnt1_part = (int*)alloc((size_t)(N_TOK / 32) * 4 * sizeof(int));
  int*   pairinfo  = (int*)alloc((size_t)N_TOK * sizeof(int));
  int*   meta      = (int*)alloc(32 * sizeof(int));
  unsigned* idx0   = (unsigned*)alloc((size_t)MT_PAD * sizeof(unsigned));
  unsigned* idx1   = (unsigned*)alloc((size_t)MT_PAD * sizeof(unsigned));

  size_t avail = (ws_size > off) ? ws_size - off : 0;
  // per padded row: xg 768*2 + HwP 3072*2 = 7680 B
  int hwrows = (int)(avail / 7680);
  if (hwrows > MT_PAD) hwrows = MT_PAD;
  hwrows &= ~127;
  if (hwrows < 128) hwrows = 128;   // pathological ws; still correct via chunking
  const int chunks = (MT_PAD + hwrows - 1) / hwrows;
  f16_t* xg  = (f16_t*)(ws + off);
  f16_t* HwP = (f16_t*)(ws + off + (size_t)hwrows * D_DIM * sizeof(f16_t));

  const int nblk = N_TOK / 32;   // router blocks = 1024

  fill_kernel<<<128, 256, 0, stream>>>(idx0, idx1);
  // W1 [E][768][3072] -> W1T tiled NT=24, KT=24
  transform_kernel<<<dim3(H_DIM / 32, D_DIM / 32, E_NUM), 256, 0, stream>>>(W1, W1T, D_DIM, H_DIM, 24, 24);
  // W2 [E][3072][768] -> W2T tiled NT=6, KT=96
  transform_kernel<<<dim3(D_DIM / 32, H_DIM / 32, E_NUM), 256, 0, stream>>>(W2, W2T, H_DIM, D_DIM, 6, 96);
  router_kernel<<<nblk, 256, 0, stream>>>(x, rw, rb, wcomb, pairinfo,
                                          psum_part, cnt_part, cnt0_part, cnt1_part);
  loss_kernel<<<1, 64, 0, stream>>>(psum_part, cnt_part, out + (size_t)N_TOK * D_DIM, nblk);
  setup_kernel<<<1, 256, 0, stream>>>(cnt0_part, cnt1_part, meta, nblk);
  scatter_kernel<<<N_TOK / 256, 256, 0, stream>>>(pairinfo, meta, idx0, idx1);

  for (int pass = 0; pass < 2; ++pass) {
    const unsigned* ip = pass ? idx1 : idx0;
    const int* pbp = meta + (pass ? 13 : 8);
    for (int c = 0; c < chunks; ++c) {
      const int srow = c * hwrows;
      gather_kernel<<<hwrows / 128, 256, 0, stream>>>(x, ip, xg, srow);
      gemm1_kernel<<<(hwrows / 128) * 24, 256, 0, stream>>>(xg, W1T, b1, pbp, HwP, srow);
      gemm2_kernel<<<(hwrows / 128) * 6, 256, 0, stream>>>(HwP, W2T, b2, wcomb, ip, pbp, out, srow, pass);
    }
  }
}

// Round 18
// 1119.578 us; speedup vs baseline: 1.1028x; 1.1028x over previous
//
#include <hip/hip_runtime.h>
#include <hip/hip_bf16.h>
#include <hip/hip_fp16.h>

// Problem constants
#define N_TOK 32768      // B*T
#define D_DIM 768
#define H_DIM 3072
#define E_NUM 4
#define MT_PAD (N_TOK + 512)   // max padded rows per pass (4 segments, 128-aligned)

// Tiled operand layout: one K-tile block = [g(4)][128 rows][8 k] f16 = 4096 elems
// = 8 KB CONTIGUOUS (matches MFMA fragment layout; staging/loads are lane-contiguous).
#define TILE_E 4096

typedef _Float16 f16_t;
typedef _Float16 f16x8 __attribute__((ext_vector_type(8)));
typedef float f32x4 __attribute__((ext_vector_type(4)));

__device__ __forceinline__ f16_t f2h(float f) { return (f16_t)f; }

// async global->LDS, 16B per lane; GLOBAL src per-lane, LDS dest wave-uniform base (+lane*16)
__device__ __forceinline__ void gload16(const void* g, void* l) {
  __builtin_amdgcn_global_load_lds(
      (const __attribute__((address_space(1))) void*)g,
      (__attribute__((address_space(3))) void*)l,
      16, 0, 0);
}

// Bijective XCD-aware remap (m204): consecutive tile ids (ntile-fastest) land on one XCD.
__device__ __forceinline__ int xcd_swizzle(int f, int nwg) {
  const int q = nwg >> 3, r = nwg & 7;
  const int xcd = f & 7, pos = f >> 3;
  return (xcd < r ? xcd * (q + 1) : r * (q + 1) + (xcd - r) * q) + pos;
}

// meta layout (ints): 8..12 pb0 | 13..17 pb1 | 18..21 cur0 | 22..25 cur1

// ---------------- init: sentinel-fill index lists ----------------
__global__ __launch_bounds__(256) void fill_kernel(unsigned* __restrict__ idx0,
                                                   unsigned* __restrict__ idx1) {
  const int t = blockIdx.x * 256 + threadIdx.x;
  for (int i = t; i < MT_PAD; i += gridDim.x * 256) {
    idx0[i] = 0xFFFFFFFFu;
    idx1[i] = 0xFFFFFFFFu;
  }
}

// ---------------- transform: fp32 [E][K][N] -> tiled f16 [E][nt][kt][g][128][8] ----
__global__ __launch_bounds__(256) void transform_kernel(
    const float* __restrict__ in, f16_t* __restrict__ outT,
    int R, int C, int NT, int KT) {   // R = K rows, C = N cols of input
  __shared__ float tile[32][33];
  const int ez = blockIdx.z;
  in += (size_t)ez * R * C;
  const int c0 = blockIdx.x * 32, r0 = blockIdx.y * 32;
  const int tc = threadIdx.x & 31, tr = threadIdx.x >> 5;
#pragma unroll
  for (int i = 0; i < 32; i += 8)
    tile[tr + i][tc] = in[(size_t)(r0 + tr + i) * C + c0 + tc];
  __syncthreads();
  const int kt = r0 >> 5, g = tc >> 3, kk = tc & 7;   // k = r0 + tc
#pragma unroll
  for (int i = 0; i < 32; i += 8) {
    const int n = c0 + tr + i;
    const int nt = n >> 7, rl = n & 127;
    outT[(((size_t)(ez * NT + nt)) * KT + kt) * TILE_E + g * 1024 + rl * 8 + kk]
        = f2h(tile[tc][tr + i]);
  }
}

// ---------------- router: softmax, top-2, pair info, block-partial counts (NO atomics) ----
__global__ __launch_bounds__(256) void router_kernel(
    const float* __restrict__ x, const float* __restrict__ rw, const float* __restrict__ rb,
    float* __restrict__ wcomb, int* __restrict__ pairinfo,
    float* __restrict__ psum_part, int* __restrict__ cnt_part,
    int* __restrict__ cnt0_part, int* __restrict__ cnt1_part) {
  __shared__ float rwT[E_NUM][D_DIM];
  __shared__ float prW[4][E_NUM];
  __shared__ int   cnW[4][E_NUM];
  __shared__ int   cn0W[4][E_NUM];
  __shared__ int   cn1W[4][E_NUM];
  const int tid = threadIdx.x;
  for (int i = tid; i < D_DIM * E_NUM; i += 256) {
    int k = i >> 2, e = i & 3;
    rwT[e][k] = rw[i];
  }
  __syncthreads();
  const int lane = tid & 63, wv_ = tid >> 6;
  float pacc[E_NUM] = {0.f, 0.f, 0.f, 0.f};
  int   cacc[E_NUM] = {0, 0, 0, 0};
  int   c0acc[E_NUM] = {0, 0, 0, 0};
  int   c1acc[E_NUM] = {0, 0, 0, 0};
  const int tok0 = blockIdx.x * 32 + wv_ * 8;
  for (int t = 0; t < 8; ++t) {
    const int m = tok0 + t;
    const float* xr = x + (size_t)m * D_DIM;
    float s0 = 0.f, s1 = 0.f, s2 = 0.f, s3 = 0.f;
#pragma unroll
    for (int i = 0; i < D_DIM / 64; ++i) {
      int k = lane + i * 64;
      float xv = xr[k];
      s0 += xv * rwT[0][k]; s1 += xv * rwT[1][k];
      s2 += xv * rwT[2][k]; s3 += xv * rwT[3][k];
    }
#pragma unroll
    for (int off = 32; off >= 1; off >>= 1) {
      s0 += __shfl_xor(s0, off); s1 += __shfl_xor(s1, off);
      s2 += __shfl_xor(s2, off); s3 += __shfl_xor(s3, off);
    }
    if (lane == 0) {
      float lg[4] = {s0 + rb[0], s1 + rb[1], s2 + rb[2], s3 + rb[3]};
      float mx = fmaxf(fmaxf(lg[0], lg[1]), fmaxf(lg[2], lg[3]));
      float p[4]; float den = 0.f;
#pragma unroll
      for (int e = 0; e < 4; ++e) { p[e] = expf(lg[e] - mx); den += p[e]; }
      float inv = 1.f / den;
#pragma unroll
      for (int e = 0; e < 4; ++e) p[e] *= inv;
      int i1 = 0;
#pragma unroll
      for (int e = 1; e < 4; ++e) if (p[e] > p[i1]) i1 = e;
      int i2 = (i1 == 0) ? 1 : 0;
#pragma unroll
      for (int e = 0; e < 4; ++e) if (e != i1 && p[e] > p[i2]) i2 = e;
      float4 wvout;
      wvout.x = (0 == i1 || 0 == i2) ? p[0] : 0.f;
      wvout.y = (1 == i1 || 1 == i2) ? p[1] : 0.f;
      wvout.z = (2 == i1 || 2 == i2) ? p[2] : 0.f;
      wvout.w = (3 == i1 || 3 == i2) ? p[3] : 0.f;
      ((float4*)wcomb)[m] = wvout;
      const int emin = (i1 < i2) ? i1 : i2;
      const int emax = (i1 < i2) ? i2 : i1;
      pairinfo[m] = emin | (emax << 4);
      c0acc[emin]++; c1acc[emax]++;
#pragma unroll
      for (int e = 0; e < 4; ++e) pacc[e] += p[e];
      cacc[i1]++; cacc[i2]++;
    }
  }
  if (lane == 0) {
#pragma unroll
    for (int e = 0; e < 4; ++e) {
      prW[wv_][e] = pacc[e]; cnW[wv_][e] = cacc[e];
      cn0W[wv_][e] = c0acc[e]; cn1W[wv_][e] = c1acc[e];
    }
  }
  __syncthreads();
  if (tid < 4) {
    float ps = prW[0][tid] + prW[1][tid] + prW[2][tid] + prW[3][tid];
    int   cs = cnW[0][tid] + cnW[1][tid] + cnW[2][tid] + cnW[3][tid];
    psum_part[blockIdx.x * 4 + tid] = ps;
    cnt_part[blockIdx.x * 4 + tid]  = cs;
    cnt0_part[blockIdx.x * 4 + tid] = cn0W[0][tid] + cn0W[1][tid] + cn0W[2][tid] + cn0W[3][tid];
    cnt1_part[blockIdx.x * 4 + tid] = cn1W[0][tid] + cn1W[1][tid] + cn1W[2][tid] + cn1W[3][tid];
  }
}

// ---------------- loss reduction (1 wave, deterministic order) ----------------
__global__ void loss_kernel(const float* __restrict__ psum_part,
                            const int* __restrict__ cnt_part,
                            float* __restrict__ loss_out, int nblk) {
  const int lane = threadIdx.x;
  float ps[4] = {0.f, 0.f, 0.f, 0.f};
  int   cs[4] = {0, 0, 0, 0};
  for (int r = lane; r < nblk; r += 64) {
#pragma unroll
    for (int e = 0; e < 4; ++e) { ps[e] += psum_part[r * 4 + e]; cs[e] += cnt_part[r * 4 + e]; }
  }
#pragma unroll
  for (int off = 32; off >= 1; off >>= 1) {
#pragma unroll
    for (int e = 0; e < 4; ++e) {
      ps[e] += __shfl_xor(ps[e], off);
      cs[e] += __shfl_xor(cs[e], off);
    }
  }
  if (lane == 0) {
    float loss = 0.f;
#pragma unroll
    for (int e = 0; e < 4; ++e) {
      float mean = ps[e] / (float)N_TOK;
      float frac = (float)cs[e] / (float)(N_TOK * 2);
      loss += mean * frac;
    }
    loss_out[0] = 4.f * loss;
  }
}

// ---------------- setup: reduce block-partial counts -> 128-padded bases + cursors ----
__global__ __launch_bounds__(256) void setup_kernel(const int* __restrict__ cnt0_part,
                                                    const int* __restrict__ cnt1_part,
                                                    int* __restrict__ meta, int nblk) {
  __shared__ int sh[8][32];
  const int ch = threadIdx.x >> 5, ln = threadIdx.x & 31;
  const int* src = (ch < 4) ? cnt0_part : cnt1_part;
  const int e = ch & 3;
  int s = 0;
  for (int b = ln; b < nblk; b += 32) s += src[b * 4 + e];
  sh[ch][ln] = s;
  __syncthreads();
  if (threadIdx.x == 0) {
    int c[8];
    for (int c2 = 0; c2 < 8; ++c2) {
      int t = 0;
      for (int l = 0; l < 32; ++l) t += sh[c2][l];
      c[c2] = t;
    }
    int pb = 0; meta[8] = 0;
    for (int e2 = 0; e2 < 4; ++e2) { pb += (c[e2] + 127) & ~127; meta[9 + e2] = pb; }
    pb = 0; meta[13] = 0;
    for (int e2 = 0; e2 < 4; ++e2) { pb += (c[4 + e2] + 127) & ~127; meta[14 + e2] = pb; }
    for (int e2 = 0; e2 < 4; ++e2) { meta[18 + e2] = meta[8 + e2]; meta[22 + e2] = meta[13 + e2]; }
  }
}

// ---------------- scatter: ballot ranks + ONE atomic per (block,channel) ----------
__global__ __launch_bounds__(256) void scatter_kernel(const int* __restrict__ pairinfo,
                                                      int* __restrict__ meta,
                                                      unsigned* __restrict__ idx0,
                                                      unsigned* __restrict__ idx1) {
  __shared__ int wcnt[2][4][4];   // [pass][wave][expert]
  __shared__ int blkbase[2][4];   // [pass][expert]
  const int tid = threadIdx.x, lane = tid & 63, wv = tid >> 6;
  const int t = blockIdx.x * 256 + tid;
  const int info = pairinfo[t];
  const int esel0 = info & 15, esel1 = info >> 4;
  int rank0 = 0, rank1 = 0;
#pragma unroll
  for (int e = 0; e < 4; ++e) {
    unsigned long long m0 = __ballot(esel0 == e);
    if (esel0 == e) rank0 = __popcll(m0 & ((1ull << lane) - 1ull));
    unsigned long long m1 = __ballot(esel1 == e);
    if (esel1 == e) rank1 = __popcll(m1 & ((1ull << lane) - 1ull));
    if (lane == 0) { wcnt[0][wv][e] = __popcll(m0); wcnt[1][wv][e] = __popcll(m1); }
  }
  __syncthreads();
  int wbase0 = 0, wbase1 = 0;
  for (int w = 0; w < wv; ++w) { wbase0 += wcnt[0][w][esel0]; wbase1 += wcnt[1][w][esel1]; }
  if (tid < 8) {
    const int p = tid >> 2, e = tid & 3;
    const int tot = wcnt[p][0][e] + wcnt[p][1][e] + wcnt[p][2][e] + wcnt[p][3][e];
    blkbase[p][e] = atomicAdd(&meta[(p ? 22 : 18) + e], tot);
  }
  __syncthreads();
  idx0[blkbase[0][esel0] + wbase0 + rank0] = (unsigned)t;
  idx1[blkbase[1][esel1] + wbase1 + rank1] = (unsigned)t;
}

// ---------------- gather: x rows (by token) -> xg tiled f16 [mt][kt24][g][128][8] ----
__global__ __launch_bounds__(256) void gather_kernel(
    const float* __restrict__ x, const unsigned* __restrict__ idx_p,
    f16_t* __restrict__ xg, int srow) {
  __shared__ unsigned idx_s[128];
  const int tid = threadIdx.x, mt = blockIdx.x;
  if (tid < 128) {
    const int gr = srow + mt * 128 + tid;
    idx_s[tid] = (gr < MT_PAD) ? idx_p[gr] : 0xFFFFFFFFu;
  }
  __syncthreads();
  f16_t* dst = xg + (size_t)mt * 24 * TILE_E;
  for (int i = tid; i < 128 * 96; i += 256) {
    const int r = i / 96, grp = i - r * 96;   // grp: 8-elem k-group (768/8)
    const unsigned v = idx_s[r];
    const float* src = x + (size_t)((v < N_TOK) ? v : 0u) * D_DIM + grp * 8;
    float4 f0 = ((const float4*)src)[0];
    float4 f1 = ((const float4*)src)[1];
    f16x8 h;
    h[0] = f2h(f0.x); h[1] = f2h(f0.y); h[2] = f2h(f0.z); h[3] = f2h(f0.w);
    h[4] = f2h(f1.x); h[5] = f2h(f1.y); h[6] = f2h(f1.z); h[7] = f2h(f1.w);
    const int kt = grp >> 2, g = grp & 3;
    *(f16x8*)&dst[(size_t)kt * TILE_E + g * 1024 + r * 8] = h;
  }
}

// ---------------- GEMMs: 128x128, BK=64, 4 waves in 4x1 grid (wave tile 32x128) ----
// r17 invariant: all configs sit at ~23 B/cyc/CU global->LDS staging rate; perf is
// set by LDS-DMA bytes per FLOP. This structure moves A to DIRECT global->register
// loads (rows are wave-private in the 4x1 grid) and stages ONLY B through LDS:
// LDS-DMA drops 15.6 -> 3.8 KB/MFLOP (4x). B LDS 16.5 KB single-buffer, plain sync
// (r16's proven loop). VGPR ~145 -> launch_bounds(256,3) cap 170, no spill.
#define BM 128
#define BN 128

#define MFMA_H(a0_, a1_, BvBase)                                                     \
  {                                                                                  \
    const f16x8* Bv = (const f16x8*)(BvBase);                                        \
    const int gsel = (lane >> 4) * 128;                                              \
    f16x8 b[8];                                                                      \
    _Pragma("unroll")                                                                \
    for (int nf = 0; nf < 8; ++nf) b[nf] = Bv[gsel + nf * 16 + (lane & 15)];         \
    _Pragma("unroll")                                                                \
    for (int nf = 0; nf < 8; ++nf)                                                   \
      acc[0][nf] = __builtin_amdgcn_mfma_f32_16x16x32_f16(a0_, b[nf], acc[0][nf], 0, 0, 0); \
    _Pragma("unroll")                                                                \
    for (int nf = 0; nf < 8; ++nf)                                                   \
      acc[1][nf] = __builtin_amdgcn_mfma_f32_16x16x32_f16(a1_, b[nf], acc[1][nf], 0, 0, 0); \
  }

// GEMM1 (sparse): HwP[prow, h] = gelu( sum_k xg_t[prow,k] * W1[e][k,h] + b1[e,h] )
__global__ __launch_bounds__(256, 3) void gemm1_kernel(
    const f16_t* __restrict__ xg, const f16_t* __restrict__ W1T,
    const float* __restrict__ b1, const int* __restrict__ pb_p,
    f16_t* __restrict__ HwP, int srow) {
  __shared__ __align__(16) f16_t Bs[2][TILE_E];
  const int tid = threadIdx.x, lane = tid & 63, wid = tid >> 6;
  const int wg = xcd_swizzle(blockIdx.x, gridDim.x);
  const int ntile = wg % 24, mtile = wg / 24;
  const int m128 = srow + mtile * BM;
  if (m128 >= pb_p[4]) return;
  int e = 0;
  while (e < 3 && m128 >= pb_p[e + 1]) ++e;
  const int n0 = ntile * BN;   // within H_DIM

  const int wr = wid;          // 4x1 wave grid: wave owns rows wr*32..wr*32+31
  const f16_t* atile = xg + (size_t)mtile * 24 * TILE_E;
  const int aoff0 = (lane >> 4) * 1024 + (wr * 32 + (lane & 15)) * 8;   // m-frag 0
  const int aoff1 = aoff0 + 16 * 8;                                     // m-frag 1
  const f16_t* bbase = W1T + (size_t)(e * 24 + ntile) * 24 * TILE_E + lane * 8;

  auto stageB = [&](int kt, int h) {
    const f16_t* b = bbase + (size_t)kt * TILE_E;
    gload16(b + wid * 512,        &Bs[h][wid * 512]);
    gload16(b + 2048 + wid * 512, &Bs[h][2048 + wid * 512]);
  };

  f32x4 acc[2][8] = {};

  float b1v[8];
#pragma unroll
  for (int nf = 0; nf < 8; ++nf)
    b1v[nf] = b1[e * H_DIM + n0 + nf * 16 + (lane & 15)];

  const int NT2 = (D_DIM / 32) / 2;  // 12 iterations of BK=64
  for (int t = 0; t < NT2; ++t) {
    stageB(2 * t, 0);
    stageB(2 * t + 1, 1);
    // direct A loads (vector path, drained by the same __syncthreads vmcnt)
    const f16_t* a0t = atile + (size_t)(2 * t) * TILE_E;
    const f16_t* a1t = atile + (size_t)(2 * t + 1) * TILE_E;
    f16x8 a00 = *(const f16x8*)(a0t + aoff0);
    f16x8 a01 = *(const f16x8*)(a0t + aoff1);
    f16x8 a10 = *(const f16x8*)(a1t + aoff0);
    f16x8 a11 = *(const f16x8*)(a1t + aoff1);
    __syncthreads();
    MFMA_H(a00, a01, Bs[0]);
    MFMA_H(a10, a11, Bs[1]);
    __syncthreads();
  }

#pragma unroll
  for (int mf = 0; mf < 2; ++mf) {
    const int rowb = wr * 32 + mf * 16 + ((lane >> 4) << 2);
#pragma unroll
    for (int nf = 0; nf < 8; ++nf) {
      const int col = n0 + nf * 16 + (lane & 15);
      const int kt = col >> 5, g = (col >> 3) & 3, kk = col & 7;
#pragma unroll
      for (int j = 0; j < 4; ++j) {
        const int row = rowb + j;
        float v = acc[mf][nf][j] + b1v[nf];
        float gel = 0.5f * v * (1.0f + erff(v * 0.70710678118654752440f));
        HwP[((size_t)(mtile * 96 + kt)) * TILE_E + g * 1024 + row * 8 + kk] = f2h(gel);
      }
    }
  }
}

// GEMM2 (sparse): contrib[tok, d] = w[tok,e] * ( sum_h HwP_t[prow,h]*W2[e][h,d] + b2[e,d] )
// pass0 (doAdd=0): out[tok] = contrib ; pass1: out[tok] += contrib. 6 ntiles, K=3072.
__global__ __launch_bounds__(256, 3) void gemm2_kernel(
    const f16_t* __restrict__ HwP, const f16_t* __restrict__ W2T,
    const float* __restrict__ b2, const float* __restrict__ wcomb,
    const unsigned* __restrict__ idx_p, const int* __restrict__ pb_p,
    float* __restrict__ out, int srow, int doAdd) {
  __shared__ __align__(16) f16_t Bs[2][TILE_E];
  __shared__ unsigned idx_s[BM];
  __shared__ float w_s[BM];
  const int tid = threadIdx.x, lane = tid & 63, wid = tid >> 6;
  const int wg = xcd_swizzle(blockIdx.x, gridDim.x);
  const int ntile = wg % 6, mtile = wg / 6;
  const int m128 = srow + mtile * BM;
  if (m128 >= pb_p[4]) return;
  int e = 0;
  while (e < 3 && m128 >= pb_p[e + 1]) ++e;
  const int n0 = ntile * BN;   // within D_DIM

  if (tid < BM) idx_s[tid] = idx_p[m128 + tid];
  __syncthreads();
  if (tid < BM) {
    unsigned v = idx_s[tid];
    w_s[tid] = (v < N_TOK) ? wcomb[v * 4 + e] : 0.f;
  }

  const int wr = wid;          // 4x1 wave grid
  const f16_t* atile = HwP + (size_t)mtile * 96 * TILE_E;
  const int aoff0 = (lane >> 4) * 1024 + (wr * 32 + (lane & 15)) * 8;
  const int aoff1 = aoff0 + 16 * 8;
  const f16_t* bbase = W2T + (size_t)(e * 6 + ntile) * 96 * TILE_E + lane * 8;

  auto stageB = [&](int kt, int h) {
    const f16_t* b = bbase + (size_t)kt * TILE_E;
    gload16(b + wid * 512,        &Bs[h][wid * 512]);
    gload16(b + 2048 + wid * 512, &Bs[h][2048 + wid * 512]);
  };

  f32x4 acc[2][8] = {};

  float b2v[8];
#pragma unroll
  for (int nf = 0; nf < 8; ++nf)
    b2v[nf] = b2[e * D_DIM + n0 + nf * 16 + (lane & 15)];

  const int NT2 = (H_DIM / 32) / 2;  // 48 iterations of BK=64
  for (int t = 0; t < NT2; ++t) {
    stageB(2 * t, 0);
    stageB(2 * t + 1, 1);
    const f16_t* a0t = atile + (size_t)(2 * t) * TILE_E;
    const f16_t* a1t = atile + (size_t)(2 * t + 1) * TILE_E;
    f16x8 a00 = *(const f16x8*)(a0t + aoff0);
    f16x8 a01 = *(const f16x8*)(a0t + aoff1);
    f16x8 a10 = *(const f16x8*)(a1t + aoff0);
    f16x8 a11 = *(const f16x8*)(a1t + aoff1);
    __syncthreads();
    MFMA_H(a00, a01, Bs[0]);
    MFMA_H(a10, a11, Bs[1]);
    __syncthreads();
  }

#pragma unroll
  for (int mf = 0; mf < 2; ++mf) {
    const int rowb = wr * 32 + mf * 16 + ((lane >> 4) << 2);
#pragma unroll
    for (int nf = 0; nf < 8; ++nf) {
      const int col = n0 + nf * 16 + (lane & 15);
#pragma unroll
      for (int j = 0; j < 4; ++j) {
        const int row = rowb + j;
        const unsigned v = idx_s[row];
        if (v < N_TOK) {
          float contrib = w_s[row] * (acc[mf][nf][j] + b2v[nf]);
          float* po = out + (size_t)v * D_DIM + col;
          if (doAdd) *po += contrib; else *po = contrib;
        }
      }
    }
  }
}

// ---------------- launch ----------------
extern "C" void kernel_launch(void* const* d_in, const int* in_sizes, int n_in,
                              void* d_out, int out_size, void* d_ws, size_t ws_size,
                              hipStream_t stream) {
  const float* x  = (const float*)d_in[0];
  const float* rw = (const float*)d_in[1];
  const float* rb = (const float*)d_in[2];
  const float* W1 = (const float*)d_in[3];
  const float* b1 = (const float*)d_in[4];
  const float* W2 = (const float*)d_in[5];
  const float* b2 = (const float*)d_in[6];
  float* out = (float*)d_out;

  char* ws = (char*)d_ws;
  size_t off = 0;
  auto alloc = [&](size_t bytes) -> void* {
    void* p = ws + off;
    off = (off + bytes + 255) & ~(size_t)255;
    return p;
  };
  f16_t* W1T = (f16_t*)alloc((size_t)E_NUM * D_DIM * H_DIM * sizeof(f16_t));
  f16_t* W2T = (f16_t*)alloc((size_t)E_NUM * D_DIM * H_DIM * sizeof(f16_t));
  float* wcomb = (float*)alloc((size_t)N_TOK * E_NUM * sizeof(float));
  float* psum_part = (float*)alloc((size_t)(N_TOK / 32) * 4 * sizeof(float));
  int*   cnt_part  = (int*)alloc((size_t)(N_TOK / 32) * 4 * sizeof(int));
  int*   cnt0_part = (int*)alloc((size_t)(N_TOK / 32) * 4 * sizeof(int));
  int*   cnt1_part = (int*)alloc((size_t)(N_TOK / 32) * 4 * sizeof(int));
  int*   pairinfo  = (int*)alloc((size_t)N_TOK * sizeof(int));
  int*   meta      = (int*)alloc(32 * sizeof(int));
  unsigned* idx0   = (unsigned*)alloc((size_t)MT_PAD * sizeof(unsigned));
  unsigned* idx1   = (unsigned*)alloc((size_t)MT_PAD * sizeof(unsigned));

  size_t avail = (ws_size > off) ? ws_size - off : 0;
  // per padded row: xg 768*2 + HwP 3072*2 = 7680 B
  int hwrows = (int)(avail / 7680);
  if (hwrows > MT_PAD) hwrows = MT_PAD;
  hwrows &= ~127;
  if (hwrows < 128) hwrows = 128;   // pathological ws; still correct via chunking
  const int chunks = (MT_PAD + hwrows - 1) / hwrows;
  f16_t* xg  = (f16_t*)(ws + off);
  f16_t* HwP = (f16_t*)(ws + off + (size_t)hwrows * D_DIM * sizeof(f16_t));

  const int nblk = N_TOK / 32;   // router blocks = 1024

  fill_kernel<<<128, 256, 0, stream>>>(idx0, idx1);
  // W1 [E][768][3072] -> W1T tiled NT=24, KT=24
  transform_kernel<<<dim3(H_DIM / 32, D_DIM / 32, E_NUM), 256, 0, stream>>>(W1, W1T, D_DIM, H_DIM, 24, 24);
  // W2 [E][3072][768] -> W2T tiled NT=6, KT=96
  transform_kernel<<<dim3(D_DIM / 32, H_DIM / 32, E_NUM), 256, 0, stream>>>(W2, W2T, H_DIM, D_DIM, 6, 96);
  router_kernel<<<nblk, 256, 0, stream>>>(x, rw, rb, wcomb, pairinfo,
                                          psum_part, cnt_part, cnt0_part, cnt1_part);
  loss_kernel<<<1, 64, 0, stream>>>(psum_part, cnt_part, out + (size_t)N_TOK * D_DIM, nblk);
  setup_kernel<<<1, 256, 0, stream>>>(cnt0_part, cnt1_part, meta, nblk);
  scatter_kernel<<<N_TOK / 256, 256, 0, stream>>>(pairinfo, meta, idx0, idx1);

  for (int pass = 0; pass < 2; ++pass) {
    const unsigned* ip = pass ? idx1 : idx0;
    const int* pbp = meta + (pass ? 13 : 8);
    for (int c = 0; c < chunks; ++c) {
      const int srow = c * hwrows;
      gather_kernel<<<hwrows / 128, 256, 0, stream>>>(x, ip, xg, srow);
      gemm1_kernel<<<(hwrows / 128) * 24, 256, 0, stream>>>(xg, W1T, b1, pbp, HwP, srow);
      gemm2_kernel<<<(hwrows / 128) * 6, 256, 0, stream>>>(HwP, W2T, b2, wcomb, ip, pbp, out, srow, pass);
    }
  }
}

// Round 19
// 1101.046 us; speedup vs baseline: 1.1214x; 1.0168x over previous
//
#include <hip/hip_runtime.h>
#include <hip/hip_bf16.h>
#include <hip/hip_fp16.h>

// Problem constants
#define N_TOK 32768      // B*T
#define D_DIM 768
#define H_DIM 3072
#define E_NUM 4
#define MT_PAD (N_TOK + 512)   // max padded rows per pass (4 segments, 128-aligned)

// Tiled operand layout: one K-tile block = [g(4)][128 rows][8 k] f16 = 4096 elems
// = 8 KB CONTIGUOUS (matches MFMA LDS fragment layout; staging is lane-contiguous).
#define TILE_E 4096

typedef _Float16 f16_t;
typedef _Float16 f16x8 __attribute__((ext_vector_type(8)));
typedef float f32x4 __attribute__((ext_vector_type(4)));

__device__ __forceinline__ f16_t f2h(float f) { return (f16_t)f; }

// async global->LDS, 16B per lane; GLOBAL src per-lane, LDS dest wave-uniform base (+lane*16)
__device__ __forceinline__ void gload16(const void* g, void* l) {
  __builtin_amdgcn_global_load_lds(
      (const __attribute__((address_space(1))) void*)g,
      (__attribute__((address_space(3))) void*)l,
      16, 0, 0);
}

// Bijective XCD-aware remap (m204): consecutive tile ids (ntile-fastest) land on one XCD.
__device__ __forceinline__ int xcd_swizzle(int f, int nwg) {
  const int q = nwg >> 3, r = nwg & 7;
  const int xcd = f & 7, pos = f >> 3;
  return (xcd < r ? xcd * (q + 1) : r * (q + 1) + (xcd - r) * q) + pos;
}

// meta layout (ints): 8..12 pb0 | 13..17 pb1 | 18..21 cur0 | 22..25 cur1

// ---------------- init: sentinel-fill index lists ----------------
__global__ __launch_bounds__(256) void fill_kernel(unsigned* __restrict__ idx0,
                                                   unsigned* __restrict__ idx1) {
  const int t = blockIdx.x * 256 + threadIdx.x;
  for (int i = t; i < MT_PAD; i += gridDim.x * 256) {
    idx0[i] = 0xFFFFFFFFu;
    idx1[i] = 0xFFFFFFFFu;
  }
}

// ---------------- transform: fp32 [E][K][N] -> tiled f16 [E][nt][kt][g][128][8] ----
__global__ __launch_bounds__(256) void transform_kernel(
    const float* __restrict__ in, f16_t* __restrict__ outT,
    int R, int C, int NT, int KT) {   // R = K rows, C = N cols of input
  __shared__ float tile[32][33];
  const int ez = blockIdx.z;
  in += (size_t)ez * R * C;
  const int c0 = blockIdx.x * 32, r0 = blockIdx.y * 32;
  const int tc = threadIdx.x & 31, tr = threadIdx.x >> 5;
#pragma unroll
  for (int i = 0; i < 32; i += 8)
    tile[tr + i][tc] = in[(size_t)(r0 + tr + i) * C + c0 + tc];
  __syncthreads();
  const int kt = r0 >> 5, g = tc >> 3, kk = tc & 7;   // k = r0 + tc
#pragma unroll
  for (int i = 0; i < 32; i += 8) {
    const int n = c0 + tr + i;
    const int nt = n >> 7, rl = n & 127;
    outT[(((size_t)(ez * NT + nt)) * KT + kt) * TILE_E + g * 1024 + rl * 8 + kk]
        = f2h(tile[tc][tr + i]);
  }
}

// ---------------- router: softmax, top-2, pair info, block-partial counts (NO atomics) ----
__global__ __launch_bounds__(256) void router_kernel(
    const float* __restrict__ x, const float* __restrict__ rw, const float* __restrict__ rb,
    float* __restrict__ wcomb, int* __restrict__ pairinfo,
    float* __restrict__ psum_part, int* __restrict__ cnt_part,
    int* __restrict__ cnt0_part, int* __restrict__ cnt1_part) {
  __shared__ float rwT[E_NUM][D_DIM];
  __shared__ float prW[4][E_NUM];
  __shared__ int   cnW[4][E_NUM];
  __shared__ int   cn0W[4][E_NUM];
  __shared__ int   cn1W[4][E_NUM];
  const int tid = threadIdx.x;
  for (int i = tid; i < D_DIM * E_NUM; i += 256) {
    int k = i >> 2, e = i & 3;
    rwT[e][k] = rw[i];
  }
  __syncthreads();
  const int lane = tid & 63, wv_ = tid >> 6;
  float pacc[E_NUM] = {0.f, 0.f, 0.f, 0.f};
  int   cacc[E_NUM] = {0, 0, 0, 0};
  int   c0acc[E_NUM] = {0, 0, 0, 0};
  int   c1acc[E_NUM] = {0, 0, 0, 0};
  const int tok0 = blockIdx.x * 32 + wv_ * 8;
  for (int t = 0; t < 8; ++t) {
    const int m = tok0 + t;
    const float* xr = x + (size_t)m * D_DIM;
    float s0 = 0.f, s1 = 0.f, s2 = 0.f, s3 = 0.f;
#pragma unroll
    for (int i = 0; i < D_DIM / 64; ++i) {
      int k = lane + i * 64;
      float xv = xr[k];
      s0 += xv * rwT[0][k]; s1 += xv * rwT[1][k];
      s2 += xv * rwT[2][k]; s3 += xv * rwT[3][k];
    }
#pragma unroll
    for (int off = 32; off >= 1; off >>= 1) {
      s0 += __shfl_xor(s0, off); s1 += __shfl_xor(s1, off);
      s2 += __shfl_xor(s2, off); s3 += __shfl_xor(s3, off);
    }
    if (lane == 0) {
      float lg[4] = {s0 + rb[0], s1 + rb[1], s2 + rb[2], s3 + rb[3]};
      float mx = fmaxf(fmaxf(lg[0], lg[1]), fmaxf(lg[2], lg[3]));
      float p[4]; float den = 0.f;
#pragma unroll
      for (int e = 0; e < 4; ++e) { p[e] = expf(lg[e] - mx); den += p[e]; }
      float inv = 1.f / den;
#pragma unroll
      for (int e = 0; e < 4; ++e) p[e] *= inv;
      int i1 = 0;
#pragma unroll
      for (int e = 1; e < 4; ++e) if (p[e] > p[i1]) i1 = e;
      int i2 = (i1 == 0) ? 1 : 0;
#pragma unroll
      for (int e = 0; e < 4; ++e) if (e != i1 && p[e] > p[i2]) i2 = e;
      float4 wvout;
      wvout.x = (0 == i1 || 0 == i2) ? p[0] : 0.f;
      wvout.y = (1 == i1 || 1 == i2) ? p[1] : 0.f;
      wvout.z = (2 == i1 || 2 == i2) ? p[2] : 0.f;
      wvout.w = (3 == i1 || 3 == i2) ? p[3] : 0.f;
      ((float4*)wcomb)[m] = wvout;
      const int emin = (i1 < i2) ? i1 : i2;
      const int emax = (i1 < i2) ? i2 : i1;
      pairinfo[m] = emin | (emax << 4);
      c0acc[emin]++; c1acc[emax]++;
#pragma unroll
      for (int e = 0; e < 4; ++e) pacc[e] += p[e];
      cacc[i1]++; cacc[i2]++;
    }
  }
  if (lane == 0) {
#pragma unroll
    for (int e = 0; e < 4; ++e) {
      prW[wv_][e] = pacc[e]; cnW[wv_][e] = cacc[e];
      cn0W[wv_][e] = c0acc[e]; cn1W[wv_][e] = c1acc[e];
    }
  }
  __syncthreads();
  if (tid < 4) {
    float ps = prW[0][tid] + prW[1][tid] + prW[2][tid] + prW[3][tid];
    int   cs = cnW[0][tid] + cnW[1][tid] + cnW[2][tid] + cnW[3][tid];
    psum_part[blockIdx.x * 4 + tid] = ps;
    cnt_part[blockIdx.x * 4 + tid]  = cs;
    cnt0_part[blockIdx.x * 4 + tid] = cn0W[0][tid] + cn0W[1][tid] + cn0W[2][tid] + cn0W[3][tid];
    cnt1_part[blockIdx.x * 4 + tid] = cn1W[0][tid] + cn1W[1][tid] + cn1W[2][tid] + cn1W[3][tid];
  }
}

// ---------------- loss reduction (1 wave, deterministic order) ----------------
__global__ void loss_kernel(const float* __restrict__ psum_part,
                            const int* __restrict__ cnt_part,
                            float* __restrict__ loss_out, int nblk) {
  const int lane = threadIdx.x;
  float ps[4] = {0.f, 0.f, 0.f, 0.f};
  int   cs[4] = {0, 0, 0, 0};
  for (int r = lane; r < nblk; r += 64) {
#pragma unroll
    for (int e = 0; e < 4; ++e) { ps[e] += psum_part[r * 4 + e]; cs[e] += cnt_part[r * 4 + e]; }
  }
#pragma unroll
  for (int off = 32; off >= 1; off >>= 1) {
#pragma unroll
    for (int e = 0; e < 4; ++e) {
      ps[e] += __shfl_xor(ps[e], off);
      cs[e] += __shfl_xor(cs[e], off);
    }
  }
  if (lane == 0) {
    float loss = 0.f;
#pragma unroll
    for (int e = 0; e < 4; ++e) {
      float mean = ps[e] / (float)N_TOK;
      float frac = (float)cs[e] / (float)(N_TOK * 2);
      loss += mean * frac;
    }
    loss_out[0] = 4.f * loss;
  }
}

// ---------------- setup: reduce block-partial counts -> 128-padded bases + cursors ----
__global__ __launch_bounds__(256) void setup_kernel(const int* __restrict__ cnt0_part,
                                                    const int* __restrict__ cnt1_part,
                                                    int* __restrict__ meta, int nblk) {
  __shared__ int sh[8][32];
  const int ch = threadIdx.x >> 5, ln = threadIdx.x & 31;
  const int* src = (ch < 4) ? cnt0_part : cnt1_part;
  const int e = ch & 3;
  int s = 0;
  for (int b = ln; b < nblk; b += 32) s += src[b * 4 + e];
  sh[ch][ln] = s;
  __syncthreads();
  if (threadIdx.x == 0) {
    int c[8];
    for (int c2 = 0; c2 < 8; ++c2) {
      int t = 0;
      for (int l = 0; l < 32; ++l) t += sh[c2][l];
      c[c2] = t;
    }
    int pb = 0; meta[8] = 0;
    for (int e2 = 0; e2 < 4; ++e2) { pb += (c[e2] + 127) & ~127; meta[9 + e2] = pb; }
    pb = 0; meta[13] = 0;
    for (int e2 = 0; e2 < 4; ++e2) { pb += (c[4 + e2] + 127) & ~127; meta[14 + e2] = pb; }
    for (int e2 = 0; e2 < 4; ++e2) { meta[18 + e2] = meta[8 + e2]; meta[22 + e2] = meta[13 + e2]; }
  }
}

// ---------------- scatter: ballot ranks + ONE atomic per (block,channel) ----------
__global__ __launch_bounds__(256) void scatter_kernel(const int* __restrict__ pairinfo,
                                                      int* __restrict__ meta,
                                                      unsigned* __restrict__ idx0,
                                                      unsigned* __restrict__ idx1) {
  __shared__ int wcnt[2][4][4];   // [pass][wave][expert]
  __shared__ int blkbase[2][4];   // [pass][expert]
  const int tid = threadIdx.x, lane = tid & 63, wv = tid >> 6;
  const int t = blockIdx.x * 256 + tid;
  const int info = pairinfo[t];
  const int esel0 = info & 15, esel1 = info >> 4;
  int rank0 = 0, rank1 = 0;
#pragma unroll
  for (int e = 0; e < 4; ++e) {
    unsigned long long m0 = __ballot(esel0 == e);
    if (esel0 == e) rank0 = __popcll(m0 & ((1ull << lane) - 1ull));
    unsigned long long m1 = __ballot(esel1 == e);
    if (esel1 == e) rank1 = __popcll(m1 & ((1ull << lane) - 1ull));
    if (lane == 0) { wcnt[0][wv][e] = __popcll(m0); wcnt[1][wv][e] = __popcll(m1); }
  }
  __syncthreads();
  int wbase0 = 0, wbase1 = 0;
  for (int w = 0; w < wv; ++w) { wbase0 += wcnt[0][w][esel0]; wbase1 += wcnt[1][w][esel1]; }
  if (tid < 8) {
    const int p = tid >> 2, e = tid & 3;
    const int tot = wcnt[p][0][e] + wcnt[p][1][e] + wcnt[p][2][e] + wcnt[p][3][e];
    blkbase[p][e] = atomicAdd(&meta[(p ? 22 : 18) + e], tot);
  }
  __syncthreads();
  idx0[blkbase[0][esel0] + wbase0 + rank0] = (unsigned)t;
  idx1[blkbase[1][esel1] + wbase1 + rank1] = (unsigned)t;
}

// ---------------- gather: x rows (by token) -> xg tiled f16 [mt][kt24][g][128][8] ----
__global__ __launch_bounds__(256) void gather_kernel(
    const float* __restrict__ x, const unsigned* __restrict__ idx_p,
    f16_t* __restrict__ xg, int srow) {
  __shared__ unsigned idx_s[128];
  const int tid = threadIdx.x, mt = blockIdx.x;
  if (tid < 128) {
    const int gr = srow + mt * 128 + tid;
    idx_s[tid] = (gr < MT_PAD) ? idx_p[gr] : 0xFFFFFFFFu;
  }
  __syncthreads();
  f16_t* dst = xg + (size_t)mt * 24 * TILE_E;
  for (int i = tid; i < 128 * 96; i += 256) {
    const int r = i / 96, grp = i - r * 96;   // grp: 8-elem k-group (768/8)
    const unsigned v = idx_s[r];
    const float* src = x + (size_t)((v < N_TOK) ? v : 0u) * D_DIM + grp * 8;
    float4 f0 = ((const float4*)src)[0];
    float4 f1 = ((const float4*)src)[1];
    f16x8 h;
    h[0] = f2h(f0.x); h[1] = f2h(f0.y); h[2] = f2h(f0.z); h[3] = f2h(f0.w);
    h[4] = f2h(f1.x); h[5] = f2h(f1.y); h[6] = f2h(f1.z); h[7] = f2h(f1.w);
    const int kt = grp >> 2, g = grp & 3;
    *(f16x8*)&dst[(size_t)kt * TILE_E + g * 1024 + r * 8] = h;
  }
}

// ---------------- GEMMs: r16 structure (BEST: 1002us). 128x128, BK=64, 4 waves,
// single-buffer LDS per 32-k half, plain sync. NEW this round: HwP chunked to
// 16640 rows (102 MB) so gemm2's A-tile reads are Infinity-Cache-resident --
// removing the ~900-cyc HBM latency exposed per iteration (gemm1 vs gemm2
// asymmetry: 923 vs 663 TF with identical structure).
#define BM 128
#define BN 128

#define MFMA_HALF(AvBase, BvBase)                                                   \
  {                                                                                 \
    const f16x8* Av = (const f16x8*)(AvBase);                                       \
    const f16x8* Bv = (const f16x8*)(BvBase);                                       \
    const int gsel = (lane >> 4) * 128;                                             \
    f16x8 a[4], b[4];                                                               \
    _Pragma("unroll")                                                               \
    for (int mf = 0; mf < 4; ++mf) a[mf] = Av[gsel + wr * 64 + mf * 16 + (lane & 15)]; \
    _Pragma("unroll")                                                               \
    for (int nf = 0; nf < 4; ++nf) b[nf] = Bv[gsel + wc * 64 + nf * 16 + (lane & 15)]; \
    _Pragma("unroll")                                                               \
    for (int mf = 0; mf < 4; ++mf)                                                  \
      _Pragma("unroll")                                                             \
      for (int nf = 0; nf < 4; ++nf)                                                \
        acc[mf][nf] = __builtin_amdgcn_mfma_f32_16x16x32_f16(a[mf], b[nf], acc[mf][nf], 0, 0, 0); \
  }

// GEMM1 (sparse): HwP[prow, h] = gelu( sum_k xg_t[prow,k] * W1[e][k,h] + b1[e,h] )
__global__ __launch_bounds__(256, 3) void gemm1_kernel(
    const f16_t* __restrict__ xg, const f16_t* __restrict__ W1T,
    const float* __restrict__ b1, const int* __restrict__ pb_p,
    f16_t* __restrict__ HwP, int srow) {
  __shared__ __align__(16) f16_t As[2 * TILE_E];
  __shared__ __align__(16) f16_t Bs[2 * TILE_E];
  const int tid = threadIdx.x, lane = tid & 63, wid = tid >> 6;
  const int wg = xcd_swizzle(blockIdx.x, gridDim.x);
  const int ntile = wg % 24, mtile = wg / 24;
  const int m128 = srow + mtile * BM;
  if (m128 >= pb_p[4]) return;
  int e = 0;
  while (e < 3 && m128 >= pb_p[e + 1]) ++e;
  const int n0 = ntile * BN;   // within H_DIM

  const f16_t* abase = xg + (size_t)mtile * 24 * TILE_E + lane * 8;
  const f16_t* bbase = W1T + (size_t)(e * 24 + ntile) * 24 * TILE_E + lane * 8;

  auto stage = [&](int kt, int h) {
    const f16_t* a = abase + (size_t)kt * TILE_E;
    const f16_t* b = bbase + (size_t)kt * TILE_E;
    gload16(a + wid * 512,        &As[h * TILE_E + wid * 512]);
    gload16(a + 2048 + wid * 512, &As[h * TILE_E + 2048 + wid * 512]);
    gload16(b + wid * 512,        &Bs[h * TILE_E + wid * 512]);
    gload16(b + 2048 + wid * 512, &Bs[h * TILE_E + 2048 + wid * 512]);
  };

  const int wr = wid >> 1, wc = wid & 1;
  f32x4 acc[4][4] = {};

  float b1v[4];
#pragma unroll
  for (int nf = 0; nf < 4; ++nf)
    b1v[nf] = b1[e * H_DIM + n0 + wc * 64 + nf * 16 + (lane & 15)];

  const int NT2 = (D_DIM / 32) / 2;  // 12 iterations of BK=64
  for (int t = 0; t < NT2; ++t) {
    stage(2 * t, 0);
    stage(2 * t + 1, 1);
    __syncthreads();          // vmcnt drain + barrier
    MFMA_HALF(As, Bs);
    MFMA_HALF(As + TILE_E, Bs + TILE_E);
    __syncthreads();          // all waves done reading before next overwrite
  }

  const int colb = wc * 64 + (lane & 15);
#pragma unroll
  for (int mf = 0; mf < 4; ++mf) {
    const int rowb = wr * 64 + mf * 16 + ((lane >> 4) << 2);
#pragma unroll
    for (int nf = 0; nf < 4; ++nf) {
      const int col = n0 + colb + nf * 16;
      const int kt = col >> 5, g = (col >> 3) & 3, kk = col & 7;
#pragma unroll
      for (int j = 0; j < 4; ++j) {
        const int row = rowb + j;
        float v = acc[mf][nf][j] + b1v[nf];
        float gel = 0.5f * v * (1.0f + erff(v * 0.70710678118654752440f));
        HwP[((size_t)(mtile * 96 + kt)) * TILE_E + g * 1024 + row * 8 + kk] = f2h(gel);
      }
    }
  }
}

// GEMM2 (sparse): contrib[tok, d] = w[tok,e] * ( sum_h HwP_t[prow,h]*W2[e][h,d] + b2[e,d] )
// pass0 (doAdd=0): out[tok] = contrib ; pass1: out[tok] += contrib. 6 ntiles, K=3072.
__global__ __launch_bounds__(256, 3) void gemm2_kernel(
    const f16_t* __restrict__ HwP, const f16_t* __restrict__ W2T,
    const float* __restrict__ b2, const float* __restrict__ wcomb,
    const unsigned* __restrict__ idx_p, const int* __restrict__ pb_p,
    float* __restrict__ out, int srow, int doAdd) {
  __shared__ __align__(16) f16_t As[2 * TILE_E];
  __shared__ __align__(16) f16_t Bs[2 * TILE_E];
  __shared__ unsigned idx_s[BM];
  __shared__ float w_s[BM];
  const int tid = threadIdx.x, lane = tid & 63, wid = tid >> 6;
  const int wg = xcd_swizzle(blockIdx.x, gridDim.x);
  const int ntile = wg % 6, mtile = wg / 6;
  const int m128 = srow + mtile * BM;
  if (m128 >= pb_p[4]) return;
  int e = 0;
  while (e < 3 && m128 >= pb_p[e + 1]) ++e;
  const int n0 = ntile * BN;   // within D_DIM

  if (tid < BM) idx_s[tid] = idx_p[m128 + tid];
  __syncthreads();
  if (tid < BM) {
    unsigned v = idx_s[tid];
    w_s[tid] = (v < N_TOK) ? wcomb[v * 4 + e] : 0.f;
  }

  const f16_t* abase = HwP + (size_t)mtile * 96 * TILE_E + lane * 8;
  const f16_t* bbase = W2T + (size_t)(e * 6 + ntile) * 96 * TILE_E + lane * 8;

  auto stage = [&](int kt, int h) {
    const f16_t* a = abase + (size_t)kt * TILE_E;
    const f16_t* b = bbase + (size_t)kt * TILE_E;
    gload16(a + wid * 512,        &As[h * TILE_E + wid * 512]);
    gload16(a + 2048 + wid * 512, &As[h * TILE_E + 2048 + wid * 512]);
    gload16(b + wid * 512,        &Bs[h * TILE_E + wid * 512]);
    gload16(b + 2048 + wid * 512, &Bs[h * TILE_E + 2048 + wid * 512]);
  };

  const int wr = wid >> 1, wc = wid & 1;
  f32x4 acc[4][4] = {};

  float b2v[4];
#pragma unroll
  for (int nf = 0; nf < 4; ++nf)
    b2v[nf] = b2[e * D_DIM + n0 + wc * 64 + nf * 16 + (lane & 15)];

  const int NT2 = (H_DIM / 32) / 2;  // 48 iterations of BK=64
  for (int t = 0; t < NT2; ++t) {
    stage(2 * t, 0);
    stage(2 * t + 1, 1);
    __syncthreads();
    MFMA_HALF(As, Bs);
    MFMA_HALF(As + TILE_E, Bs + TILE_E);
    __syncthreads();
  }

  const int colb = wc * 64 + (lane & 15);
#pragma unroll
  for (int mf = 0; mf < 4; ++mf) {
    const int rowb = wr * 64 + mf * 16 + ((lane >> 4) << 2);
#pragma unroll
    for (int nf = 0; nf < 4; ++nf) {
      const int col = n0 + colb + nf * 16;
#pragma unroll
      for (int j = 0; j < 4; ++j) {
        const int row = rowb + j;
        const unsigned v = idx_s[row];
        if (v < N_TOK) {
          float contrib = w_s[row] * (acc[mf][nf][j] + b2v[nf]);
          float* po = out + (size_t)v * D_DIM + col;
          if (doAdd) *po += contrib; else *po = contrib;
        }
      }
    }
  }
}

// ---------------- launch ----------------
extern "C" void kernel_launch(void* const* d_in, const int* in_sizes, int n_in,
                              void* d_out, int out_size, void* d_ws, size_t ws_size,
                              hipStream_t stream) {
  const float* x  = (const float*)d_in[0];
  const float* rw = (const float*)d_in[1];
  const float* rb = (const float*)d_in[2];
  const float* W1 = (const float*)d_in[3];
  const float* b1 = (const float*)d_in[4];
  const float* W2 = (const float*)d_in[5];
  const float* b2 = (const float*)d_in[6];
  float* out = (float*)d_out;

  char* ws = (char*)d_ws;
  size_t off = 0;
  auto alloc = [&](size_t bytes) -> void* {
    void* p = ws + off;
    off = (off + bytes + 255) & ~(size_t)255;
    return p;
  };
  f16_t* W1T = (f16_t*)alloc((size_t)E_NUM * D_DIM * H_DIM * sizeof(f16_t));
  f16_t* W2T = (f16_t*)alloc((size_t)E_NUM * D_DIM * H_DIM * sizeof(f16_t));
  float* wcomb = (float*)alloc((size_t)N_TOK * E_NUM * sizeof(float));
  float* psum_part = (float*)alloc((size_t)(N_TOK / 32) * 4 * sizeof(float));
  int*   cnt_part  = (int*)alloc((size_t)(N_TOK / 32) * 4 * sizeof(int));
  int*   cnt0_part = (int*)alloc((size_t)(N_TOK / 32) * 4 * sizeof(int));
  int*   cnt1_part = (int*)alloc((size_t)(N_TOK / 32) * 4 * sizeof(int));
  int*   pairinfo  = (int*)alloc((size_t)N_TOK * sizeof(int));
  int*   meta      = (int*)alloc(32 * sizeof(int));
  unsigned* idx0   = (unsigned*)alloc((size_t)MT_PAD * sizeof(unsigned));
  unsigned* idx1   = (unsigned*)alloc((size_t)MT_PAD * sizeof(unsigned));

  size_t avail = (ws_size > off) ? ws_size - off : 0;
  // per padded row: xg 768*2 + HwP 3072*2 = 7680 B
  int hwrows = (int)(avail / 7680);
  if (hwrows > 16640) hwrows = 16640;   // HwP chunk = 102 MB -> L3-resident for gemm2
  hwrows &= ~127;
  if (hwrows < 128) hwrows = 128;   // pathological ws; still correct via chunking
  const int chunks = (MT_PAD + hwrows - 1) / hwrows;
  f16_t* xg  = (f16_t*)(ws + off);
  f16_t* HwP = (f16_t*)(ws + off + (size_t)hwrows * D_DIM * sizeof(f16_t));

  const int nblk = N_TOK / 32;   // router blocks = 1024

  fill_kernel<<<128, 256, 0, stream>>>(idx0, idx1);
  // W1 [E][768][3072] -> W1T tiled NT=24, KT=24
  transform_kernel<<<dim3(H_DIM / 32, D_DIM / 32, E_NUM), 256, 0, stream>>>(W1, W1T, D_DIM, H_DIM, 24, 24);
  // W2 [E][3072][768] -> W2T tiled NT=6, KT=96
  transform_kernel<<<dim3(D_DIM / 32, H_DIM / 32, E_NUM), 256, 0, stream>>>(W2, W2T, H_DIM, D_DIM, 6, 96);
  router_kernel<<<nblk, 256, 0, stream>>>(x, rw, rb, wcomb, pairinfo,
                                          psum_part, cnt_part, cnt0_part, cnt1_part);
  loss_kernel<<<1, 64, 0, stream>>>(psum_part, cnt_part, out + (size_t)N_TOK * D_DIM, nblk);
  setup_kernel<<<1, 256, 0, stream>>>(cnt0_part, cnt1_part, meta, nblk);
  scatter_kernel<<<N_TOK / 256, 256, 0, stream>>>(pairinfo, meta, idx0, idx1);

  for (int pass = 0; pass < 2; ++pass) {
    const unsigned* ip = pass ? idx1 : idx0;
    const int* pbp = meta + (pass ? 13 : 8);
    for (int c = 0; c < chunks; ++c) {
      const int srow = c * hwrows;
      gather_kernel<<<hwrows / 128, 256, 0, stream>>>(x, ip, xg, srow);
      gemm1_kernel<<<(hwrows / 128) * 24, 256, 0, stream>>>(xg, W1T, b1, pbp, HwP, srow);
      gemm2_kernel<<<(hwrows / 128) * 6, 256, 0, stream>>>(HwP, W2T, b2, wcomb, ip, pbp, out, srow, pass);
    }
  }
}

// Round 20
// 999.105 us; speedup vs baseline: 1.2358x; 1.1020x over previous
//
#include <hip/hip_runtime.h>
#include <hip/hip_bf16.h>
#include <hip/hip_fp16.h>

// Problem constants
#define N_TOK 32768      // B*T
#define D_DIM 768
#define H_DIM 3072
#define E_NUM 4
#define MT_PAD (N_TOK + 512)   // max padded rows per pass (4 segments, 128-aligned)

// Tiled operand layout: one K-tile block = [g(4)][128 rows][8 k] f16 = 4096 elems
// = 8 KB CONTIGUOUS (matches MFMA LDS fragment layout; staging is lane-contiguous).
#define TILE_E 4096

typedef _Float16 f16_t;
typedef _Float16 f16x8 __attribute__((ext_vector_type(8)));
typedef float f32x4 __attribute__((ext_vector_type(4)));

__device__ __forceinline__ f16_t f2h(float f) { return (f16_t)f; }

// async global->LDS, 16B per lane; GLOBAL src per-lane, LDS dest wave-uniform base (+lane*16)
__device__ __forceinline__ void gload16(const void* g, void* l) {
  __builtin_amdgcn_global_load_lds(
      (const __attribute__((address_space(1))) void*)g,
      (__attribute__((address_space(3))) void*)l,
      16, 0, 0);
}

// Bijective XCD-aware remap (m204): consecutive tile ids (ntile-fastest) land on one XCD.
__device__ __forceinline__ int xcd_swizzle(int f, int nwg) {
  const int q = nwg >> 3, r = nwg & 7;
  const int xcd = f & 7, pos = f >> 3;
  return (xcd < r ? xcd * (q + 1) : r * (q + 1) + (xcd - r) * q) + pos;
}

// meta layout (ints): 8..12 pb0 | 13..17 pb1 | 18..21 cur0 | 22..25 cur1

// ---------------- init: sentinel-fill index lists ----------------
__global__ __launch_bounds__(256) void fill_kernel(unsigned* __restrict__ idx0,
                                                   unsigned* __restrict__ idx1) {
  const int t = blockIdx.x * 256 + threadIdx.x;
  for (int i = t; i < MT_PAD; i += gridDim.x * 256) {
    idx0[i] = 0xFFFFFFFFu;
    idx1[i] = 0xFFFFFFFFu;
  }
}

// ---------------- transform: fp32 [E][K][N] -> tiled f16 [E][nt][kt][g][128][8] ----
__global__ __launch_bounds__(256) void transform_kernel(
    const float* __restrict__ in, f16_t* __restrict__ outT,
    int R, int C, int NT, int KT) {   // R = K rows, C = N cols of input
  __shared__ float tile[32][33];
  const int ez = blockIdx.z;
  in += (size_t)ez * R * C;
  const int c0 = blockIdx.x * 32, r0 = blockIdx.y * 32;
  const int tc = threadIdx.x & 31, tr = threadIdx.x >> 5;
#pragma unroll
  for (int i = 0; i < 32; i += 8)
    tile[tr + i][tc] = in[(size_t)(r0 + tr + i) * C + c0 + tc];
  __syncthreads();
  const int kt = r0 >> 5, g = tc >> 3, kk = tc & 7;   // k = r0 + tc
#pragma unroll
  for (int i = 0; i < 32; i += 8) {
    const int n = c0 + tr + i;
    const int nt = n >> 7, rl = n & 127;
    outT[(((size_t)(ez * NT + nt)) * KT + kt) * TILE_E + g * 1024 + rl * 8 + kk]
        = f2h(tile[tc][tr + i]);
  }
}

// ---------------- router: softmax, top-2, pair info, block-partial counts (NO atomics) ----
__global__ __launch_bounds__(256) void router_kernel(
    const float* __restrict__ x, const float* __restrict__ rw, const float* __restrict__ rb,
    float* __restrict__ wcomb, int* __restrict__ pairinfo,
    float* __restrict__ psum_part, int* __restrict__ cnt_part,
    int* __restrict__ cnt0_part, int* __restrict__ cnt1_part) {
  __shared__ float rwT[E_NUM][D_DIM];
  __shared__ float prW[4][E_NUM];
  __shared__ int   cnW[4][E_NUM];
  __shared__ int   cn0W[4][E_NUM];
  __shared__ int   cn1W[4][E_NUM];
  const int tid = threadIdx.x;
  for (int i = tid; i < D_DIM * E_NUM; i += 256) {
    int k = i >> 2, e = i & 3;
    rwT[e][k] = rw[i];
  }
  __syncthreads();
  const int lane = tid & 63, wv_ = tid >> 6;
  float pacc[E_NUM] = {0.f, 0.f, 0.f, 0.f};
  int   cacc[E_NUM] = {0, 0, 0, 0};
  int   c0acc[E_NUM] = {0, 0, 0, 0};
  int   c1acc[E_NUM] = {0, 0, 0, 0};
  const int tok0 = blockIdx.x * 32 + wv_ * 8;
  for (int t = 0; t < 8; ++t) {
    const int m = tok0 + t;
    const float* xr = x + (size_t)m * D_DIM;
    float s0 = 0.f, s1 = 0.f, s2 = 0.f, s3 = 0.f;
#pragma unroll
    for (int i = 0; i < D_DIM / 64; ++i) {
      int k = lane + i * 64;
      float xv = xr[k];
      s0 += xv * rwT[0][k]; s1 += xv * rwT[1][k];
      s2 += xv * rwT[2][k]; s3 += xv * rwT[3][k];
    }
#pragma unroll
    for (int off = 32; off >= 1; off >>= 1) {
      s0 += __shfl_xor(s0, off); s1 += __shfl_xor(s1, off);
      s2 += __shfl_xor(s2, off); s3 += __shfl_xor(s3, off);
    }
    if (lane == 0) {
      float lg[4] = {s0 + rb[0], s1 + rb[1], s2 + rb[2], s3 + rb[3]};
      float mx = fmaxf(fmaxf(lg[0], lg[1]), fmaxf(lg[2], lg[3]));
      float p[4]; float den = 0.f;
#pragma unroll
      for (int e = 0; e < 4; ++e) { p[e] = expf(lg[e] - mx); den += p[e]; }
      float inv = 1.f / den;
#pragma unroll
      for (int e = 0; e < 4; ++e) p[e] *= inv;
      int i1 = 0;
#pragma unroll
      for (int e = 1; e < 4; ++e) if (p[e] > p[i1]) i1 = e;
      int i2 = (i1 == 0) ? 1 : 0;
#pragma unroll
      for (int e = 0; e < 4; ++e) if (e != i1 && p[e] > p[i2]) i2 = e;
      float4 wvout;
      wvout.x = (0 == i1 || 0 == i2) ? p[0] : 0.f;
      wvout.y = (1 == i1 || 1 == i2) ? p[1] : 0.f;
      wvout.z = (2 == i1 || 2 == i2) ? p[2] : 0.f;
      wvout.w = (3 == i1 || 3 == i2) ? p[3] : 0.f;
      ((float4*)wcomb)[m] = wvout;
      const int emin = (i1 < i2) ? i1 : i2;
      const int emax = (i1 < i2) ? i2 : i1;
      pairinfo[m] = emin | (emax << 4);
      c0acc[emin]++; c1acc[emax]++;
#pragma unroll
      for (int e = 0; e < 4; ++e) pacc[e] += p[e];
      cacc[i1]++; cacc[i2]++;
    }
  }
  if (lane == 0) {
#pragma unroll
    for (int e = 0; e < 4; ++e) {
      prW[wv_][e] = pacc[e]; cnW[wv_][e] = cacc[e];
      cn0W[wv_][e] = c0acc[e]; cn1W[wv_][e] = c1acc[e];
    }
  }
  __syncthreads();
  if (tid < 4) {
    float ps = prW[0][tid] + prW[1][tid] + prW[2][tid] + prW[3][tid];
    int   cs = cnW[0][tid] + cnW[1][tid] + cnW[2][tid] + cnW[3][tid];
    psum_part[blockIdx.x * 4 + tid] = ps;
    cnt_part[blockIdx.x * 4 + tid]  = cs;
    cnt0_part[blockIdx.x * 4 + tid] = cn0W[0][tid] + cn0W[1][tid] + cn0W[2][tid] + cn0W[3][tid];
    cnt1_part[blockIdx.x * 4 + tid] = cn1W[0][tid] + cn1W[1][tid] + cn1W[2][tid] + cn1W[3][tid];
  }
}

// ---------------- loss reduction (1 wave, deterministic order) ----------------
__global__ void loss_kernel(const float* __restrict__ psum_part,
                            const int* __restrict__ cnt_part,
                            float* __restrict__ loss_out, int nblk) {
  const int lane = threadIdx.x;
  float ps[4] = {0.f, 0.f, 0.f, 0.f};
  int   cs[4] = {0, 0, 0, 0};
  for (int r = lane; r < nblk; r += 64) {
#pragma unroll
    for (int e = 0; e < 4; ++e) { ps[e] += psum_part[r * 4 + e]; cs[e] += cnt_part[r * 4 + e]; }
  }
#pragma unroll
  for (int off = 32; off >= 1; off >>= 1) {
#pragma unroll
    for (int e = 0; e < 4; ++e) {
      ps[e] += __shfl_xor(ps[e], off);
      cs[e] += __shfl_xor(cs[e], off);
    }
  }
  if (lane == 0) {
    float loss = 0.f;
#pragma unroll
    for (int e = 0; e < 4; ++e) {
      float mean = ps[e] / (float)N_TOK;
      float frac = (float)cs[e] / (float)(N_TOK * 2);
      loss += mean * frac;
    }
    loss_out[0] = 4.f * loss;
  }
}

// ---------------- setup: reduce block-partial counts -> 128-padded bases + cursors ----
__global__ __launch_bounds__(256) void setup_kernel(const int* __restrict__ cnt0_part,
                                                    const int* __restrict__ cnt1_part,
                                                    int* __restrict__ meta, int nblk) {
  __shared__ int sh[8][32];
  const int ch = threadIdx.x >> 5, ln = threadIdx.x & 31;
  const int* src = (ch < 4) ? cnt0_part : cnt1_part;
  const int e = ch & 3;
  int s = 0;
  for (int b = ln; b < nblk; b += 32) s += src[b * 4 + e];
  sh[ch][ln] = s;
  __syncthreads();
  if (threadIdx.x == 0) {
    int c[8];
    for (int c2 = 0; c2 < 8; ++c2) {
      int t = 0;
      for (int l = 0; l < 32; ++l) t += sh[c2][l];
      c[c2] = t;
    }
    int pb = 0; meta[8] = 0;
    for (int e2 = 0; e2 < 4; ++e2) { pb += (c[e2] + 127) & ~127; meta[9 + e2] = pb; }
    pb = 0; meta[13] = 0;
    for (int e2 = 0; e2 < 4; ++e2) { pb += (c[4 + e2] + 127) & ~127; meta[14 + e2] = pb; }
    for (int e2 = 0; e2 < 4; ++e2) { meta[18 + e2] = meta[8 + e2]; meta[22 + e2] = meta[13 + e2]; }
  }
}

// ---------------- scatter: ballot ranks + ONE atomic per (block,channel) ----------
__global__ __launch_bounds__(256) void scatter_kernel(const int* __restrict__ pairinfo,
                                                      int* __restrict__ meta,
                                                      unsigned* __restrict__ idx0,
                                                      unsigned* __restrict__ idx1) {
  __shared__ int wcnt[2][4][4];   // [pass][wave][expert]
  __shared__ int blkbase[2][4];   // [pass][expert]
  const int tid = threadIdx.x, lane = tid & 63, wv = tid >> 6;
  const int t = blockIdx.x * 256 + tid;
  const int info = pairinfo[t];
  const int esel0 = info & 15, esel1 = info >> 4;
  int rank0 = 0, rank1 = 0;
#pragma unroll
  for (int e = 0; e < 4; ++e) {
    unsigned long long m0 = __ballot(esel0 == e);
    if (esel0 == e) rank0 = __popcll(m0 & ((1ull << lane) - 1ull));
    unsigned long long m1 = __ballot(esel1 == e);
    if (esel1 == e) rank1 = __popcll(m1 & ((1ull << lane) - 1ull));
    if (lane == 0) { wcnt[0][wv][e] = __popcll(m0); wcnt[1][wv][e] = __popcll(m1); }
  }
  __syncthreads();
  int wbase0 = 0, wbase1 = 0;
  for (int w = 0; w < wv; ++w) { wbase0 += wcnt[0][w][esel0]; wbase1 += wcnt[1][w][esel1]; }
  if (tid < 8) {
    const int p = tid >> 2, e = tid & 3;
    const int tot = wcnt[p][0][e] + wcnt[p][1][e] + wcnt[p][2][e] + wcnt[p][3][e];
    blkbase[p][e] = atomicAdd(&meta[(p ? 22 : 18) + e], tot);
  }
  __syncthreads();
  idx0[blkbase[0][esel0] + wbase0 + rank0] = (unsigned)t;
  idx1[blkbase[1][esel1] + wbase1 + rank1] = (unsigned)t;
}

// ---------------- gather: x rows (by token) -> xg tiled f16 [mt][kt24][g][128][8] ----
__global__ __launch_bounds__(256) void gather_kernel(
    const float* __restrict__ x, const unsigned* __restrict__ idx_p,
    f16_t* __restrict__ xg, int srow) {
  __shared__ unsigned idx_s[128];
  const int tid = threadIdx.x, mt = blockIdx.x;
  if (tid < 128) {
    const int gr = srow + mt * 128 + tid;
    idx_s[tid] = (gr < MT_PAD) ? idx_p[gr] : 0xFFFFFFFFu;
  }
  __syncthreads();
  f16_t* dst = xg + (size_t)mt * 24 * TILE_E;
  for (int i = tid; i < 128 * 96; i += 256) {
    const int r = i / 96, grp = i - r * 96;   // grp: 8-elem k-group (768/8)
    const unsigned v = idx_s[r];
    const float* src = x + (size_t)((v < N_TOK) ? v : 0u) * D_DIM + grp * 8;
    float4 f0 = ((const float4*)src)[0];
    float4 f1 = ((const float4*)src)[1];
    f16x8 h;
    h[0] = f2h(f0.x); h[1] = f2h(f0.y); h[2] = f2h(f0.z); h[3] = f2h(f0.w);
    h[4] = f2h(f1.x); h[5] = f2h(f1.y); h[6] = f2h(f1.z); h[7] = f2h(f1.w);
    const int kt = grp >> 2, g = grp & 3;
    *(f16x8*)&dst[(size_t)kt * TILE_E + g * 1024 + r * 8] = h;
  }
}

// ---------------- GEMMs: r16 BEST config (1002us). 128x128, BK=64 (two 32-k halves
// per barrier pair), 4 waves, single-buffer LDS, plain sync. All schedule variants
// (depth-2/3 vmcnt pipelines, 3-buffer rotation, 256x128 8-wave, A-direct-reg,
// L3 chunking) measured null-to-negative (r8-r19); this is the structural optimum
// of the family.
#define BM 128
#define BN 128

#define MFMA_HALF(AvBase, BvBase)                                                   \
  {                                                                                 \
    const f16x8* Av = (const f16x8*)(AvBase);                                       \
    const f16x8* Bv = (const f16x8*)(BvBase);                                       \
    const int gsel = (lane >> 4) * 128;                                             \
    f16x8 a[4], b[4];                                                               \
    _Pragma("unroll")                                                               \
    for (int mf = 0; mf < 4; ++mf) a[mf] = Av[gsel + wr * 64 + mf * 16 + (lane & 15)]; \
    _Pragma("unroll")                                                               \
    for (int nf = 0; nf < 4; ++nf) b[nf] = Bv[gsel + wc * 64 + nf * 16 + (lane & 15)]; \
    _Pragma("unroll")                                                               \
    for (int mf = 0; mf < 4; ++mf)                                                  \
      _Pragma("unroll")                                                             \
      for (int nf = 0; nf < 4; ++nf)                                                \
        acc[mf][nf] = __builtin_amdgcn_mfma_f32_16x16x32_f16(a[mf], b[nf], acc[mf][nf], 0, 0, 0); \
  }

// GEMM1 (sparse): HwP[prow, h] = gelu( sum_k xg_t[prow,k] * W1[e][k,h] + b1[e,h] )
__global__ __launch_bounds__(256, 3) void gemm1_kernel(
    const f16_t* __restrict__ xg, const f16_t* __restrict__ W1T,
    const float* __restrict__ b1, const int* __restrict__ pb_p,
    f16_t* __restrict__ HwP, int srow) {
  __shared__ __align__(16) f16_t As[2 * TILE_E];
  __shared__ __align__(16) f16_t Bs[2 * TILE_E];
  const int tid = threadIdx.x, lane = tid & 63, wid = tid >> 6;
  const int wg = xcd_swizzle(blockIdx.x, gridDim.x);
  const int ntile = wg % 24, mtile = wg / 24;
  const int m128 = srow + mtile * BM;
  if (m128 >= pb_p[4]) return;
  int e = 0;
  while (e < 3 && m128 >= pb_p[e + 1]) ++e;
  const int n0 = ntile * BN;   // within H_DIM

  const f16_t* abase = xg + (size_t)mtile * 24 * TILE_E + lane * 8;
  const f16_t* bbase = W1T + (size_t)(e * 24 + ntile) * 24 * TILE_E + lane * 8;

  auto stage = [&](int kt, int h) {
    const f16_t* a = abase + (size_t)kt * TILE_E;
    const f16_t* b = bbase + (size_t)kt * TILE_E;
    gload16(a + wid * 512,        &As[h * TILE_E + wid * 512]);
    gload16(a + 2048 + wid * 512, &As[h * TILE_E + 2048 + wid * 512]);
    gload16(b + wid * 512,        &Bs[h * TILE_E + wid * 512]);
    gload16(b + 2048 + wid * 512, &Bs[h * TILE_E + 2048 + wid * 512]);
  };

  const int wr = wid >> 1, wc = wid & 1;
  f32x4 acc[4][4] = {};

  float b1v[4];
#pragma unroll
  for (int nf = 0; nf < 4; ++nf)
    b1v[nf] = b1[e * H_DIM + n0 + wc * 64 + nf * 16 + (lane & 15)];

  const int NT2 = (D_DIM / 32) / 2;  // 12 iterations of BK=64
  for (int t = 0; t < NT2; ++t) {
    stage(2 * t, 0);
    stage(2 * t + 1, 1);
    __syncthreads();          // vmcnt drain + barrier
    MFMA_HALF(As, Bs);
    MFMA_HALF(As + TILE_E, Bs + TILE_E);
    __syncthreads();          // all waves done reading before next overwrite
  }

  const int colb = wc * 64 + (lane & 15);
#pragma unroll
  for (int mf = 0; mf < 4; ++mf) {
    const int rowb = wr * 64 + mf * 16 + ((lane >> 4) << 2);
#pragma unroll
    for (int nf = 0; nf < 4; ++nf) {
      const int col = n0 + colb + nf * 16;
      const int kt = col >> 5, g = (col >> 3) & 3, kk = col & 7;
#pragma unroll
      for (int j = 0; j < 4; ++j) {
        const int row = rowb + j;
        float v = acc[mf][nf][j] + b1v[nf];
        float gel = 0.5f * v * (1.0f + erff(v * 0.70710678118654752440f));
        HwP[((size_t)(mtile * 96 + kt)) * TILE_E + g * 1024 + row * 8 + kk] = f2h(gel);
      }
    }
  }
}

// GEMM2 (sparse): contrib[tok, d] = w[tok,e] * ( sum_h HwP_t[prow,h]*W2[e][h,d] + b2[e,d] )
// pass0 (doAdd=0): out[tok] = contrib ; pass1: out[tok] += contrib. 6 ntiles, K=3072.
__global__ __launch_bounds__(256, 3) void gemm2_kernel(
    const f16_t* __restrict__ HwP, const f16_t* __restrict__ W2T,
    const float* __restrict__ b2, const float* __restrict__ wcomb,
    const unsigned* __restrict__ idx_p, const int* __restrict__ pb_p,
    float* __restrict__ out, int srow, int doAdd) {
  __shared__ __align__(16) f16_t As[2 * TILE_E];
  __shared__ __align__(16) f16_t Bs[2 * TILE_E];
  __shared__ unsigned idx_s[BM];
  __shared__ float w_s[BM];
  const int tid = threadIdx.x, lane = tid & 63, wid = tid >> 6;
  const int wg = xcd_swizzle(blockIdx.x, gridDim.x);
  const int ntile = wg % 6, mtile = wg / 6;
  const int m128 = srow + mtile * BM;
  if (m128 >= pb_p[4]) return;
  int e = 0;
  while (e < 3 && m128 >= pb_p[e + 1]) ++e;
  const int n0 = ntile * BN;   // within D_DIM

  if (tid < BM) idx_s[tid] = idx_p[m128 + tid];
  __syncthreads();
  if (tid < BM) {
    unsigned v = idx_s[tid];
    w_s[tid] = (v < N_TOK) ? wcomb[v * 4 + e] : 0.f;
  }

  const f16_t* abase = HwP + (size_t)mtile * 96 * TILE_E + lane * 8;
  const f16_t* bbase = W2T + (size_t)(e * 6 + ntile) * 96 * TILE_E + lane * 8;

  auto stage = [&](int kt, int h) {
    const f16_t* a = abase + (size_t)kt * TILE_E;
    const f16_t* b = bbase + (size_t)kt * TILE_E;
    gload16(a + wid * 512,        &As[h * TILE_E + wid * 512]);
    gload16(a + 2048 + wid * 512, &As[h * TILE_E + 2048 + wid * 512]);
    gload16(b + wid * 512,        &Bs[h * TILE_E + wid * 512]);
    gload16(b + 2048 + wid * 512, &Bs[h * TILE_E + 2048 + wid * 512]);
  };

  const int wr = wid >> 1, wc = wid & 1;
  f32x4 acc[4][4] = {};

  float b2v[4];
#pragma unroll
  for (int nf = 0; nf < 4; ++nf)
    b2v[nf] = b2[e * D_DIM + n0 + wc * 64 + nf * 16 + (lane & 15)];

  const int NT2 = (H_DIM / 32) / 2;  // 48 iterations of BK=64
  for (int t = 0; t < NT2; ++t) {
    stage(2 * t, 0);
    stage(2 * t + 1, 1);
    __syncthreads();
    MFMA_HALF(As, Bs);
    MFMA_HALF(As + TILE_E, Bs + TILE_E);
    __syncthreads();
  }

  const int colb = wc * 64 + (lane & 15);
#pragma unroll
  for (int mf = 0; mf < 4; ++mf) {
    const int rowb = wr * 64 + mf * 16 + ((lane >> 4) << 2);
#pragma unroll
    for (int nf = 0; nf < 4; ++nf) {
      const int col = n0 + colb + nf * 16;
#pragma unroll
      for (int j = 0; j < 4; ++j) {
        const int row = rowb + j;
        const unsigned v = idx_s[row];
        if (v < N_TOK) {
          float contrib = w_s[row] * (acc[mf][nf][j] + b2v[nf]);
          float* po = out + (size_t)v * D_DIM + col;
          if (doAdd) *po += contrib; else *po = contrib;
        }
      }
    }
  }
}

// ---------------- launch ----------------
extern "C" void kernel_launch(void* const* d_in, const int* in_sizes, int n_in,
                              void* d_out, int out_size, void* d_ws, size_t ws_size,
                              hipStream_t stream) {
  const float* x  = (const float*)d_in[0];
  const float* rw = (const float*)d_in[1];
  const float* rb = (const float*)d_in[2];
  const float* W1 = (const float*)d_in[3];
  const float* b1 = (const float*)d_in[4];
  const float* W2 = (const float*)d_in[5];
  const float* b2 = (const float*)d_in[6];
  float* out = (float*)d_out;

  char* ws = (char*)d_ws;
  size_t off = 0;
  auto alloc = [&](size_t bytes) -> void* {
    void* p = ws + off;
    off = (off + bytes + 255) & ~(size_t)255;
    return p;
  };
  f16_t* W1T = (f16_t*)alloc((size_t)E_NUM * D_DIM * H_DIM * sizeof(f16_t));
  f16_t* W2T = (f16_t*)alloc((size_t)E_NUM * D_DIM * H_DIM * sizeof(f16_t));
  float* wcomb = (float*)alloc((size_t)N_TOK * E_NUM * sizeof(float));
  float* psum_part = (float*)alloc((size_t)(N_TOK / 32) * 4 * sizeof(float));
  int*   cnt_part  = (int*)alloc((size_t)(N_TOK / 32) * 4 * sizeof(int));
  int*   cnt0_part = (int*)alloc((size_t)(N_TOK / 32) * 4 * sizeof(int));
  int*   cnt1_part = (int*)alloc((size_t)(N_TOK / 32) * 4 * sizeof(int));
  int*   pairinfo  = (int*)alloc((size_t)N_TOK * sizeof(int));
  int*   meta      = (int*)alloc(32 * sizeof(int));
  unsigned* idx0   = (unsigned*)alloc((size_t)MT_PAD * sizeof(unsigned));
  unsigned* idx1   = (unsigned*)alloc((size_t)MT_PAD * sizeof(unsigned));

  size_t avail = (ws_size > off) ? ws_size - off : 0;
  // per padded row: xg 768*2 + HwP 3072*2 = 7680 B
  int hwrows = (int)(avail / 7680);
  if (hwrows > MT_PAD) hwrows = MT_PAD;
  hwrows &= ~127;
  if (hwrows < 128) hwrows = 128;   // pathological ws; still correct via chunking
  const int chunks = (MT_PAD + hwrows - 1) / hwrows;
  f16_t* xg  = (f16_t*)(ws + off);
  f16_t* HwP = (f16_t*)(ws + off + (size_t)hwrows * D_DIM * sizeof(f16_t));

  const int nblk = N_TOK / 32;   // router blocks = 1024

  fill_kernel<<<128, 256, 0, stream>>>(idx0, idx1);
  // W1 [E][768][3072] -> W1T tiled NT=24, KT=24
  transform_kernel<<<dim3(H_DIM / 32, D_DIM / 32, E_NUM), 256, 0, stream>>>(W1, W1T, D_DIM, H_DIM, 24, 24);
  // W2 [E][3072][768] -> W2T tiled NT=6, KT=96
  transform_kernel<<<dim3(D_DIM / 32, H_DIM / 32, E_NUM), 256, 0, stream>>>(W2, W2T, H_DIM, D_DIM, 6, 96);
  router_kernel<<<nblk, 256, 0, stream>>>(x, rw, rb, wcomb, pairinfo,
                                          psum_part, cnt_part, cnt0_part, cnt1_part);
  loss_kernel<<<1, 64, 0, stream>>>(psum_part, cnt_part, out + (size_t)N_TOK * D_DIM, nblk);
  setup_kernel<<<1, 256, 0, stream>>>(cnt0_part, cnt1_part, meta, nblk);
  scatter_kernel<<<N_TOK / 256, 256, 0, stream>>>(pairinfo, meta, idx0, idx1);

  for (int pass = 0; pass < 2; ++pass) {
    const unsigned* ip = pass ? idx1 : idx0;
    const int* pbp = meta + (pass ? 13 : 8);
    for (int c = 0; c < chunks; ++c) {
      const int srow = c * hwrows;
      gather_kernel<<<hwrows / 128, 256, 0, stream>>>(x, ip, xg, srow);
      gemm1_kernel<<<(hwrows / 128) * 24, 256, 0, stream>>>(xg, W1T, b1, pbp, HwP, srow);
      gemm2_kernel<<<(hwrows / 128) * 6, 256, 0, stream>>>(HwP, W2T, b2, wcomb, ip, pbp, out, srow, pass);
    }
  }
}